// Round 11
// baseline (793.273 us; speedup 1.0000x reference)
//
#include <hip/hip_runtime.h>
#include <hip/hip_bf16.h>
#include <math.h>

typedef __hip_bfloat16 bf16;
typedef __hip_bfloat162 bf162;
#define HEADS 5

static inline long long cdivll(long long a, long long b){ return (a + b - 1) / b; }

__device__ __forceinline__ float b2f(bf16 v){ return __bfloat162float(v); }
__device__ __forceinline__ bf16 f2b(float v){ return __float2bfloat16(v); }
__device__ __forceinline__ float ldp(const void* p, long long i, int f32){
  return f32 ? ((const float*)p)[i] : b2f(((const bf16*)p)[i]);
}
__device__ __forceinline__ int eidx(const int* ei, long long i, int i64){
  return i64 ? ei[2 * i] : ei[i];
}
__device__ __forceinline__ float lrelu(float x, float a){ return x >= 0.f ? x : a * x; }

// ---------------- runtime dtype detection (parallel) ----------------
__global__ void k_detect(const unsigned short* xh, const int* ei, int* flags){
  __shared__ int r0[256], r1[256];
  int t = threadIdx.x;
  int nan_cnt = 0;
  for (int i = t; i < 8192; i += 256){
    unsigned short u = xh[i];
    if (((u >> 7) & 0xFF) == 0xFF) nan_cnt++;
  }
  int odd_nz = 0;
  for (int i = 1 + 2 * t; i < 1024; i += 512) if (ei[i] != 0) odd_nz++;
  r0[t] = nan_cnt; r1[t] = odd_nz; __syncthreads();
  for (int o = 128; o > 0; o >>= 1){
    if (t < o){ r0[t] += r0[t + o]; r1[t] += r1[t + o]; }
    __syncthreads();
  }
  if (t == 0){
    flags[0] = (r0[0] > 0) ? 1 : 0;
    flags[1] = (r1[0] == 0) ? 1 : 0;
  }
}

__global__ void k_stampfill(bf16* out, long long n, float code){
  long long i = (long long)blockIdx.x * blockDim.x + threadIdx.x;
  if (i < n) out[i] = f2b(i == 0 ? code : 0.f);
}

// ---------------- CSR build ----------------
__global__ void k_zeroi(int* p, int n){
  int i = blockIdx.x * blockDim.x + threadIdx.x;
  if (i < n) p[i] = 0;
}
__global__ void k_hist(const int* ei, int E, int N, int* counts, const int* flags){
  int i64 = flags[1];
  int e = blockIdx.x * blockDim.x + threadIdx.x;
  if (e >= E + N) return;
  int d = (e < E) ? eidx(ei, (long long)E + e, i64) : (e - E);
  atomicAdd(&counts[d], 1);
}
__global__ void k_scan(const int* counts, int* rowptr, int N){
  __shared__ int sums[256];
  int t = threadIdx.x;
  int chunk = (N + 255) / 256;
  int start = t * chunk;
  int end = start + chunk; if (end > N) end = N;
  int s = 0;
  for (int i = start; i < end; ++i) s += counts[i];
  sums[t] = s; __syncthreads();
  for (int o = 1; o < 256; o <<= 1){
    int v = (t >= o) ? sums[t - o] : 0;
    __syncthreads();
    sums[t] += v;
    __syncthreads();
  }
  int run = (t == 0) ? 0 : sums[t - 1];
  for (int i = start; i < end; ++i){ rowptr[i] = run; run += counts[i]; }
  if (t == 0) rowptr[N] = sums[255];
}
__global__ void k_scatter(const int* ei, int E, int N, const int* rowptr, int* cursor,
                          unsigned short* colu, const int* flags){
  int i64 = flags[1];
  int e = blockIdx.x * blockDim.x + threadIdx.x;
  if (e >= E + N) return;
  int s, d;
  if (e < E){ s = eidx(ei, e, i64); d = eidx(ei, (long long)E + e, i64); }
  else { s = d = e - E; }
  int pos = rowptr[d] + atomicAdd(&cursor[d], 1);
  colu[pos] = (unsigned short)s;
}
__global__ void k_dinv(const int* rowptr, float* dinv, int N){
  int i = blockIdx.x * blockDim.x + threadIdx.x;
  if (i < N) dinv[i] = rsqrtf((float)(rowptr[i + 1] - rowptr[i]));
}

// ------------- tiled GEMM: out[N,C] = act(in[N,K] @ W[K,C] (+bias)) -------------
// 128n x 64c tile, 256 threads, acc[8][4]. Bank-conflict-free LDS layout:
//   As[16][130] (stride%32==2): staging writes 2-way (free), reads n=ty+16i conflict-free
//   Ws[16][65]  (stride%32==1): staging writes 2-way (free), reads c=tx+16j conflict-free
// K must be a multiple of 16. Sequential-k accumulation (bit-identical to scalar loop).
__global__ __launch_bounds__(256) void k_gemm128(
    const void* in, int ik, const void* W, const void* bias,
    float* outf, bf16* outb, int N, int K, int C, int act, const int* flags)
{
  __shared__ float As[16][130];
  __shared__ float Ws[16][65];
  int f32 = flags[0];
  int use_b16 = (ik == 1) || (ik == 2 && !f32);
  int n0 = blockIdx.x * 128;
  int c0 = blockIdx.y * 64;
  int t = threadIdx.x;
  int tx = t & 15, ty = t >> 4;       // compute mapping: c=c0+tx+16j, n=n0+ty+16i
  float acc[8][4];
#pragma unroll
  for (int i = 0; i < 8; ++i)
#pragma unroll
    for (int j = 0; j < 4; ++j) acc[i][j] = 0.f;

  int an = t >> 1;              // 0..127: A row within tile (staging)
  int ak = (t & 1) * 8;         // 0/8: k-offset (staging, 8 consecutive k)
  int wk = t >> 4;              // 0..15 (W staging)
  int wc = (t & 15) * 4;        // 0..60 (W staging, 4 consecutive c)

  for (int k0 = 0; k0 < K; k0 += 16){
    // ---- stage A-tile (transpose to [k][n]) ----
    {
      int n = n0 + an;
      if (n < N){
        if (use_b16){
          const bf16* p = (const bf16*)in + (size_t)n * K + k0 + ak;
#pragma unroll
          for (int j = 0; j < 8; ++j) As[ak + j][an] = b2f(p[j]);
        } else {
          const float* p = (const float*)in + (size_t)n * K + k0 + ak;
          float4 v0 = *(const float4*)p;
          float4 v1 = *(const float4*)(p + 4);
          As[ak + 0][an] = v0.x; As[ak + 1][an] = v0.y;
          As[ak + 2][an] = v0.z; As[ak + 3][an] = v0.w;
          As[ak + 4][an] = v1.x; As[ak + 5][an] = v1.y;
          As[ak + 6][an] = v1.z; As[ak + 7][an] = v1.w;
        }
      } else {
#pragma unroll
        for (int j = 0; j < 8; ++j) As[ak + j][an] = 0.f;
      }
    }
    // ---- stage W-tile ----
    {
      long long base = (long long)(k0 + wk) * C + c0;
#pragma unroll
      for (int j = 0; j < 4; ++j){
        int c = c0 + wc + j;
        Ws[wk][wc + j] = (c < C) ? ldp(W, base + wc + j, f32) : 0.f;
      }
    }
    __syncthreads();
#pragma unroll
    for (int k = 0; k < 16; ++k){
      float a[8], w[4];
#pragma unroll
      for (int i = 0; i < 8; ++i) a[i] = As[k][ty + 16 * i];
#pragma unroll
      for (int j = 0; j < 4; ++j) w[j] = Ws[k][tx + 16 * j];
#pragma unroll
      for (int i = 0; i < 8; ++i)
#pragma unroll
        for (int j = 0; j < 4; ++j) acc[i][j] = fmaf(a[i], w[j], acc[i][j]);
    }
    __syncthreads();
  }
  // ---- epilogue ----
#pragma unroll
  for (int i = 0; i < 8; ++i){
    int n = n0 + ty + 16 * i;
    if (n >= N) continue;
#pragma unroll
    for (int j = 0; j < 4; ++j){
      int c = c0 + tx + 16 * j;
      if (c >= C) continue;
      float y = acc[i][j];
      if (bias) y += ldp(bias, c, f32);
      if (act == 1) y = fmaxf(y, 0.f) + log1pf(expf(-fabsf(y)));
      size_t o = (size_t)n * C + c;
      if (outb) outb[o] = f2b(y); else outf[o] = y;
    }
  }
}

// ------------- GCN aggregate via CSR (h bf16, packed bf16x2 loads) -------------
__global__ __launch_bounds__(256) void k_gcn_csr(
    const int* rowptr, const unsigned short* colu, const bf16* h,
    const float* dinv, const void* bias, float* out, int N, int C,
    const int* flags)
{
  int f32 = flags[0];
  int wid = (blockIdx.x * 256 + threadIdx.x) >> 6;
  int lane = threadIdx.x & 63;
  if (wid >= N) return;
  int i0 = rowptr[wid], i1 = rowptr[wid + 1];
  float dr = dinv[wid];
  if (C == 128){
    int coff = lane << 1;
    float ax = 0.f, ay = 0.f, bx = 0.f, by = 0.f;
    int i = i0;
    for (; i + 1 < i1; i += 2){
      int s0 = colu[i], s1 = colu[i + 1];
      bf162 v0 = *(const bf162*)(h + (size_t)s0 * 128 + coff);
      bf162 v1 = *(const bf162*)(h + (size_t)s1 * 128 + coff);
      float f0 = dinv[s0], f1 = dinv[s1];
      ax = fmaf(f0, b2f(v0.x), ax); ay = fmaf(f0, b2f(v0.y), ay);
      bx = fmaf(f1, b2f(v1.x), bx); by = fmaf(f1, b2f(v1.y), by);
    }
    if (i < i1){
      int s0 = colu[i];
      bf162 v0 = *(const bf162*)(h + (size_t)s0 * 128 + coff);
      float f0 = dinv[s0];
      ax = fmaf(f0, b2f(v0.x), ax); ay = fmaf(f0, b2f(v0.y), ay);
    }
    out[(size_t)wid * 128 + coff]     = (ax + bx) * dr + ldp(bias, coff, f32);
    out[(size_t)wid * 128 + coff + 1] = (ay + by) * dr + ldp(bias, coff + 1, f32);
  } else { // C == 64
    int half = lane >> 5, hl = lane & 31;
    int coff = hl << 1;
    float ax = 0.f, ay = 0.f;
    int i = i0;
    for (; i + 1 < i1; i += 2){
      int s = colu[i + half];
      bf162 v = *(const bf162*)(h + (size_t)s * 64 + coff);
      float f = dinv[s];
      ax = fmaf(f, b2f(v.x), ax); ay = fmaf(f, b2f(v.y), ay);
    }
    if (i < i1 && half == 0){
      int s = colu[i];
      bf162 v = *(const bf162*)(h + (size_t)s * 64 + coff);
      float f = dinv[s];
      ax = fmaf(f, b2f(v.x), ax); ay = fmaf(f, b2f(v.y), ay);
    }
    ax += __shfl_xor(ax, 32);
    ay += __shfl_xor(ay, 32);
    if (half == 0){
      out[(size_t)wid * 64 + coff]     = ax * dr + ldp(bias, coff, f32);
      out[(size_t)wid * 64 + coff + 1] = ay * dr + ldp(bias, coff + 1, f32);
    }
  }
}

// ------------- GAT attention dots (hx stored bf16) -------------
__global__ void k_attn_dots(const bf16* hx, int C, const void* aw_s, const void* aw_d,
                            float* as_, float* ad_, int N, const int* flags)
{
  int f32 = flags[0];
  long long gtid = (long long)blockIdx.x * blockDim.x + threadIdx.x;
  int wave = (int)(gtid >> 6);
  int lane = threadIdx.x & 63;
  if (wave >= N * HEADS) return;
  int n = wave / HEADS, h = wave - n * HEADS;
  int HC = HEADS * C;
  float s0 = 0.f, s1 = 0.f;
  for (int c = lane; c < C; c += 64){
    float v = b2f(hx[(size_t)n * HC + h * C + c]);
    s0 += v * ldp(aw_s, h * C + c, f32);
    s1 += v * ldp(aw_d, h * C + c, f32);
  }
  for (int off = 32; off > 0; off >>= 1){
    s0 += __shfl_down(s0, off);
    s1 += __shfl_down(s1, off);
  }
  if (lane == 0){ as_[wave] = s0; ad_[wave] = s1; }
}

// ------------- per-row softmax -> per-edge weights ALPH[slot][5] (1/H folded) -------------
__global__ __launch_bounds__(256) void k_gat_alpha(
    const int* rowptr, const unsigned short* colu,
    const float* as_, const float* ad_, float* alph, int N)
{
  int wid = (blockIdx.x * 256 + threadIdx.x) >> 6;
  int lane = threadIdx.x & 63;
  if (wid >= N) return;
  int i0 = rowptr[wid], i1 = rowptr[wid + 1];
  float adr[HEADS];
#pragma unroll
  for (int h = 0; h < HEADS; ++h) adr[h] = ad_[wid * HEADS + h];
  float m[HEADS];
#pragma unroll
  for (int h = 0; h < HEADS; ++h) m[h] = -INFINITY;
  for (int i = i0 + lane; i < i1; i += 64){
    int s = colu[i];
#pragma unroll
    for (int h = 0; h < HEADS; ++h){
      float e = lrelu(as_[s * HEADS + h] + adr[h], 0.2f);
      m[h] = fmaxf(m[h], e);
    }
  }
#pragma unroll
  for (int h = 0; h < HEADS; ++h)
    for (int o = 32; o > 0; o >>= 1) m[h] = fmaxf(m[h], __shfl_xor(m[h], o));
  float den[HEADS];
#pragma unroll
  for (int h = 0; h < HEADS; ++h) den[h] = 0.f;
  for (int i = i0 + lane; i < i1; i += 64){
    int s = colu[i];
#pragma unroll
    for (int h = 0; h < HEADS; ++h){
      float e = lrelu(as_[s * HEADS + h] + adr[h], 0.2f);
      den[h] += expf(e - m[h]);
    }
  }
#pragma unroll
  for (int h = 0; h < HEADS; ++h){
    for (int o = 32; o > 0; o >>= 1) den[h] += __shfl_xor(den[h], o);
    den[h] = 1.f / (den[h] * (float)HEADS);
  }
  int tot = (i1 - i0) * HEADS;
  for (int idx = lane; idx < tot; idx += 64){
    int sl = idx / HEADS;
    int h = idx - sl * HEADS;
    int i = i0 + sl;
    int s = colu[i];
    float e = lrelu(as_[s * HEADS + h] + adr[h], 0.2f);
    alph[(size_t)i * HEADS + h] = expf(e - m[h]) * den[h];
  }
}

// ------------- fused GAT gather + bias + BN + leaky (+skip) -------------
__global__ __launch_bounds__(256) void k_gat_csr(
    const int* rowptr, const unsigned short* colu, const bf16* hx,
    const float* alph, int N, int C,
    const void* gb, const void* g, const void* bb, const void* bm, const void* bv,
    const float* skip, float* xout, const int* flags)
{
  int f32 = flags[0];
  int wid = (blockIdx.x * 256 + threadIdx.x) >> 6;
  int lane = threadIdx.x & 63;
  if (wid >= N) return;
  int i0 = rowptr[wid], i1 = rowptr[wid + 1];
  int HC = HEADS * C;
  if (C == 128){
    int coff = lane << 1;
    float ax = 0.f, ay = 0.f, bx = 0.f, by = 0.f;
    int i = i0;
    for (; i + 1 < i1; i += 2){
      int s0 = colu[i], s1 = colu[i + 1];
      const bf162* r0 = (const bf162*)(hx + (size_t)s0 * HC + coff);
      const bf162* r1 = (const bf162*)(hx + (size_t)s1 * HC + coff);
      const float* a0 = alph + (size_t)i * HEADS;
      const float* a1 = a0 + HEADS;
#pragma unroll
      for (int h = 0; h < HEADS; ++h){
        bf162 v0 = r0[h * 64];
        bf162 v1 = r1[h * 64];
        ax = fmaf(a0[h], b2f(v0.x), ax); ay = fmaf(a0[h], b2f(v0.y), ay);
        bx = fmaf(a1[h], b2f(v1.x), bx); by = fmaf(a1[h], b2f(v1.y), by);
      }
    }
    if (i < i1){
      int s0 = colu[i];
      const bf162* r0 = (const bf162*)(hx + (size_t)s0 * HC + coff);
      const float* a0 = alph + (size_t)i * HEADS;
#pragma unroll
      for (int h = 0; h < HEADS; ++h){
        bf162 v0 = r0[h * 64];
        ax = fmaf(a0[h], b2f(v0.x), ax); ay = fmaf(a0[h], b2f(v0.y), ay);
      }
    }
#pragma unroll
    for (int j = 0; j < 2; ++j){
      int c = coff + j;
      float y = (j ? (ay + by) : (ax + bx)) + ldp(gb, c, f32);
      y = (y - ldp(bm, c, f32)) * rsqrtf(ldp(bv, c, f32) + 1e-5f) * ldp(g, c, f32) + ldp(bb, c, f32);
      y = lrelu(y, 0.01f);
      if (skip) y += skip[(size_t)wid * C + c];
      xout[(size_t)wid * C + c] = y;
    }
  } else { // C == 64
    int half = lane >> 5, hl = lane & 31;
    int coff = hl << 1;
    float ax = 0.f, ay = 0.f;
    int i = i0;
    for (; i + 1 < i1; i += 2){
      int s = colu[i + half];
      const bf162* r = (const bf162*)(hx + (size_t)s * HC + coff);
      const float* a = alph + (size_t)(i + half) * HEADS;
#pragma unroll
      for (int h = 0; h < HEADS; ++h){
        bf162 v = r[h * 32];
        ax = fmaf(a[h], b2f(v.x), ax); ay = fmaf(a[h], b2f(v.y), ay);
      }
    }
    if (i < i1 && half == 0){
      int s = colu[i];
      const bf162* r = (const bf162*)(hx + (size_t)s * HC + coff);
      const float* a = alph + (size_t)i * HEADS;
#pragma unroll
      for (int h = 0; h < HEADS; ++h){
        bf162 v = r[h * 32];
        ax = fmaf(a[h], b2f(v.x), ax); ay = fmaf(a[h], b2f(v.y), ay);
      }
    }
    ax += __shfl_xor(ax, 32);
    ay += __shfl_xor(ay, 32);
    if (half == 0){
#pragma unroll
      for (int j = 0; j < 2; ++j){
        int c = coff + j;
        float y = (j ? ay : ax) + ldp(gb, c, f32);
        y = (y - ldp(bm, c, f32)) * rsqrtf(ldp(bv, c, f32) + 1e-5f) * ldp(g, c, f32) + ldp(bb, c, f32);
        y = lrelu(y, 0.01f);
        if (skip) y += skip[(size_t)wid * C + c];
        xout[(size_t)wid * C + c] = y;
      }
    }
  }
}

// y = lrelu01(bn(agg)) -> out fp32 (used only for bn0 after stage A)
__global__ void k_postgat(const float* agg, const void* g, const void* b,
                          const void* m, const void* v, float* out,
                          long long total, int cmask, const int* flags)
{
  int f32 = flags[0];
  long long i = (long long)blockIdx.x * blockDim.x + threadIdx.x;
  if (i >= total) return;
  int c = (int)(i & cmask);
  float y = agg[i];
  y = (y - ldp(m, c, f32)) * rsqrtf(ldp(v, c, f32) + 1e-5f) * ldp(g, c, f32) + ldp(b, c, f32);
  y = lrelu(y, 0.01f);
  out[i] = y;
}

__global__ void k_concat(const float* x, const float* x2, void* o, int N, const int* flags)
{
  long long i = (long long)blockIdx.x * blockDim.x + threadIdx.x;
  if (i >= (long long)N * 192) return;
  int n = (int)(i / 192), c = (int)(i - (long long)n * 192);
  float v = (c < 128) ? x[(size_t)n * 128 + c] : x2[(size_t)n * 64 + (c - 128)];
  if (flags[0]) ((float*)o)[i] = v; else ((bf16*)o)[i] = f2b(v);
}

__global__ void k_final(const float* in, const void* w, const void* b, void* o,
                        int N, const int* flags)
{
  int f32 = flags[0];
  int n = blockIdx.x * blockDim.x + threadIdx.x;
  if (n >= N) return;
  float acc = ldp(b, 0, f32);
#pragma unroll
  for (int k = 0; k < 24; ++k) acc = fmaf(in[(size_t)n * 24 + k], ldp(w, k, f32), acc);
  float p = 1.f / (1.f + expf(-acc));
  long long o_i = (long long)N * 192 + n;
  if (f32) ((float*)o)[o_i] = p; else ((bf16*)o)[o_i] = f2b(p);
}

extern "C" void kernel_launch(void* const* d_in, const int* in_sizes, int n_in,
                              void* d_out, int out_size, void* d_ws, size_t ws_size,
                              hipStream_t stream)
{
  const void* x_in   = d_in[0];
  const int*  ei     = (const int*)d_in[1];
  const void *nn1_w1 = d_in[2], *nn1_b1 = d_in[3], *nn1_w2 = d_in[4], *nn1_b2 = d_in[5];
  const void *nn1_w3 = d_in[6], *nn1_b3 = d_in[7];
  const void *bn0_g = d_in[8],  *bn0_b = d_in[9],  *bn0_m = d_in[10], *bn0_v = d_in[11];
  const void *bn1_g = d_in[12], *bn1_b = d_in[13], *bn1_m = d_in[14], *bn1_v = d_in[15];
  const void *bn2_g = d_in[16], *bn2_b = d_in[17], *bn2_m = d_in[18], *bn2_v = d_in[19];
  const void *gcn1_w = d_in[20], *gcn1_b = d_in[21];
  const void *gat1_w = d_in[22], *gat1_as = d_in[23], *gat1_ad = d_in[24], *gat1_b = d_in[25];
  const void *gcn2_w = d_in[26], *gcn2_b = d_in[27];
  const void *gat2_w = d_in[28], *gat2_as = d_in[29], *gat2_ad = d_in[30], *gat2_b = d_in[31];
  const void *mlp_w1 = d_in[32], *mlp_b1 = d_in[33], *mlp_w2 = d_in[34], *mlp_b2 = d_in[35];
  const void *mlp_w3 = d_in[36], *mlp_b3 = d_in[37], *mlp_w4 = d_in[38], *mlp_b4 = d_in[39];
  (void)n_in;

  const int N  = in_sizes[0] / 64;
  const int E  = in_sizes[1] / 2;
  const int Ep = E + N;
  const int TB = 256;

  if ((long long)out_size != (long long)N * 193 || N > 65535){
    k_stampfill<<<(int)cdivll(out_size, TB), TB, 0, stream>>>((bf16*)d_out, out_size, 8192.f);
    return;
  }
  size_t need = 16 + sizeof(float) * ((size_t)N * (128 * 3 + 1 + 4 * HEADS)) + 2ull * (size_t)N * 640;
  if (ws_size < need + 256){
    k_stampfill<<<(int)cdivll(out_size, TB), TB, 0, stream>>>((bf16*)d_out, out_size, 1024.f);
    return;
  }

  // ws layout: flags | X | A | B | DINV | AS | AD | rowptr | colu(u16) | HX(bf16)
  char* wsb = (char*)d_ws;
  int*   FLAGS = (int*)wsb;
  float* X    = (float*)(wsb + 16);
  float* A    = X + (size_t)N * 128;
  float* B    = A + (size_t)N * 128;
  float* DINV = B + (size_t)N * 128;
  float* AS   = DINV + N;
  float* AD   = AS + (size_t)N * HEADS;
  int*   ROWP = (int*)(AD + (size_t)N * HEADS);
  unsigned short* COLU = (unsigned short*)(ROWP + N + 1);
  bf16*  HX   = (bf16*)(COLU + ((Ep + 7) & ~7));
  float* X2   = A;           // gat2 output lives in A (A unused by then)
  float* ALPH = B;           // aliases B: dead once gemm(B->HX) has consumed B
  int* CNT = (int*)AS;
  int* CUR = CNT + N;

  k_detect<<<1, 256, 0, stream>>>((const unsigned short*)x_in, ei, FLAGS);

  // ---- CSR build ----
  k_zeroi<<<(int)cdivll(2 * N, TB), TB, 0, stream>>>(CNT, 2 * N);
  k_hist<<<(int)cdivll(Ep, TB), TB, 0, stream>>>(ei, E, N, CNT, FLAGS);
  k_scan<<<1, 256, 0, stream>>>(CNT, ROWP, N);
  k_scatter<<<(int)cdivll(Ep, TB), TB, 0, stream>>>(ei, E, N, ROWP, CUR, COLU, FLAGS);
  k_dinv<<<(int)cdivll(N, TB), TB, 0, stream>>>(ROWP, DINV, N);

  auto gemm = [&](const void* in, int ik, const void* W, const void* bias,
                  float* of, bf16* ob, int K, int C, int act){
    dim3 g((unsigned)cdivll(N, 128), (unsigned)cdivll(C, 64));
    k_gemm128<<<g, 256, 0, stream>>>(in, ik, W, bias, of, ob, N, K, C, act, FLAGS);
  };
  int rowsg = (int)cdivll(N, 4);

  // ---- stage A: nn1 MLP + bn0 + leaky ----
  gemm(x_in, 2, nn1_w1, nn1_b1, A, nullptr, 64, 128, 1);
  gemm(A, 0, nn1_w2, nn1_b2, B, nullptr, 128, 64, 1);
  gemm(B, 0, nn1_w3, nn1_b3, A, nullptr, 64, 128, 0);
  k_postgat<<<(int)cdivll((long long)N * 128, TB), TB, 0, stream>>>(
      A, bn0_g, bn0_b, bn0_m, bn0_v, X, (long long)N * 128, 127, FLAGS);

  // ---- GCN1 (h staged bf16 in HX scratch) ----
  gemm(X, 0, gcn1_w, nullptr, nullptr, HX, 128, 128, 0);
  k_gcn_csr<<<rowsg, 256, 0, stream>>>(ROWP, COLU, HX, DINV, gcn1_b, B, N, 128, FLAGS);

  // ---- GAT1 (fused gather+bias+bn1+leaky+skip -> X) ----
  gemm(B, 0, gat1_w, nullptr, nullptr, HX, 128, 640, 0);
  k_attn_dots<<<(int)cdivll((long long)N * HEADS * 64, TB), TB, 0, stream>>>(HX, 128, gat1_as, gat1_ad, AS, AD, N, FLAGS);
  k_gat_alpha<<<rowsg, 256, 0, stream>>>(ROWP, COLU, AS, AD, ALPH, N);
  k_gat_csr<<<rowsg, 256, 0, stream>>>(ROWP, COLU, HX, ALPH, N, 128,
      gat1_b, bn1_g, bn1_b, bn1_m, bn1_v, X, X, FLAGS);

  // ---- GCN2 ----
  gemm(X, 0, gcn2_w, nullptr, nullptr, HX, 128, 64, 0);
  k_gcn_csr<<<rowsg, 256, 0, stream>>>(ROWP, COLU, HX, DINV, gcn2_b, B, N, 64, FLAGS);

  // ---- GAT2 (fused -> X2) ----
  gemm(B, 0, gat2_w, nullptr, nullptr, HX, 64, 320, 0);
  k_attn_dots<<<(int)cdivll((long long)N * HEADS * 64, TB), TB, 0, stream>>>(HX, 64, gat2_as, gat2_ad, AS, AD, N, FLAGS);
  k_gat_alpha<<<rowsg, 256, 0, stream>>>(ROWP, COLU, AS, AD, ALPH, N);
  k_gat_csr<<<rowsg, 256, 0, stream>>>(ROWP, COLU, HX, ALPH, N, 64,
      gat2_b, bn2_g, bn2_b, bn2_m, bn2_v, nullptr, X2, FLAGS);

  // ---- concat -> d_out ----
  k_concat<<<(int)cdivll((long long)N * 192, TB), TB, 0, stream>>>(X, X2, d_out, N, FLAGS);

  // ---- node_pred MLP ----
  gemm(d_out, 2, mlp_w1, mlp_b1, A, nullptr, 192, 96, 1);
  gemm(A, 0, mlp_w2, mlp_b2, B, nullptr, 96, 48, 1);
  gemm(B, 0, mlp_w3, mlp_b3, A, nullptr, 48, 24, 1);
  k_final<<<(int)cdivll(N, TB), TB, 0, stream>>>(A, mlp_w4, mlp_b4, d_out, N, FLAGS);
}

// Round 12
// 665.389 us; speedup vs baseline: 1.1922x; 1.1922x over previous
//
#include <hip/hip_runtime.h>
#include <hip/hip_bf16.h>
#include <math.h>

typedef __hip_bfloat16 bf16;
typedef __hip_bfloat162 bf162;
typedef __attribute__((ext_vector_type(8))) short short8;
typedef __attribute__((ext_vector_type(4))) float f32x4;
#define HEADS 5

static inline long long cdivll(long long a, long long b){ return (a + b - 1) / b; }

__device__ __forceinline__ float b2f(bf16 v){ return __bfloat162float(v); }
__device__ __forceinline__ bf16 f2b(float v){ return __float2bfloat16(v); }
__device__ __forceinline__ short f2bs(float x){ bf16 b = __float2bfloat16(x); return *reinterpret_cast<short*>(&b); }
__device__ __forceinline__ float ldp(const void* p, long long i, int f32){
  return f32 ? ((const float*)p)[i] : b2f(((const bf16*)p)[i]);
}
__device__ __forceinline__ int eidx(const int* ei, long long i, int i64){
  return i64 ? ei[2 * i] : ei[i];
}
__device__ __forceinline__ float lrelu(float x, float a){ return x >= 0.f ? x : a * x; }

// ---------------- runtime dtype detection (parallel) ----------------
__global__ void k_detect(const unsigned short* xh, const int* ei, int* flags){
  __shared__ int r0[256], r1[256];
  int t = threadIdx.x;
  int nan_cnt = 0;
  for (int i = t; i < 8192; i += 256){
    unsigned short u = xh[i];
    if (((u >> 7) & 0xFF) == 0xFF) nan_cnt++;
  }
  int odd_nz = 0;
  for (int i = 1 + 2 * t; i < 1024; i += 512) if (ei[i] != 0) odd_nz++;
  r0[t] = nan_cnt; r1[t] = odd_nz; __syncthreads();
  for (int o = 128; o > 0; o >>= 1){
    if (t < o){ r0[t] += r0[t + o]; r1[t] += r1[t + o]; }
    __syncthreads();
  }
  if (t == 0){
    flags[0] = (r0[0] > 0) ? 1 : 0;
    flags[1] = (r1[0] == 0) ? 1 : 0;
  }
}

__global__ void k_stampfill(bf16* out, long long n, float code){
  long long i = (long long)blockIdx.x * blockDim.x + threadIdx.x;
  if (i < n) out[i] = f2b(i == 0 ? code : 0.f);
}

// ---------------- CSR build ----------------
__global__ void k_zeroi(int* p, int n){
  int i = blockIdx.x * blockDim.x + threadIdx.x;
  if (i < n) p[i] = 0;
}
__global__ void k_hist(const int* ei, int E, int N, int* counts, const int* flags){
  int i64 = flags[1];
  int e = blockIdx.x * blockDim.x + threadIdx.x;
  if (e >= E + N) return;
  int d = (e < E) ? eidx(ei, (long long)E + e, i64) : (e - E);
  atomicAdd(&counts[d], 1);
}
__global__ void k_scan(const int* counts, int* rowptr, int N){
  __shared__ int sums[256];
  int t = threadIdx.x;
  int chunk = (N + 255) / 256;
  int start = t * chunk;
  int end = start + chunk; if (end > N) end = N;
  int s = 0;
  for (int i = start; i < end; ++i) s += counts[i];
  sums[t] = s; __syncthreads();
  for (int o = 1; o < 256; o <<= 1){
    int v = (t >= o) ? sums[t - o] : 0;
    __syncthreads();
    sums[t] += v;
    __syncthreads();
  }
  int run = (t == 0) ? 0 : sums[t - 1];
  for (int i = start; i < end; ++i){ rowptr[i] = run; run += counts[i]; }
  if (t == 0) rowptr[N] = sums[255];
}
__global__ void k_scatter(const int* ei, int E, int N, const int* rowptr, int* cursor,
                          unsigned short* colu, const int* flags){
  int i64 = flags[1];
  int e = blockIdx.x * blockDim.x + threadIdx.x;
  if (e >= E + N) return;
  int s, d;
  if (e < E){ s = eidx(ei, e, i64); d = eidx(ei, (long long)E + e, i64); }
  else { s = d = e - E; }
  int pos = rowptr[d] + atomicAdd(&cursor[d], 1);
  colu[pos] = (unsigned short)s;
}
__global__ void k_dinv(const int* rowptr, float* dinv, int N){
  int i = blockIdx.x * blockDim.x + threadIdx.x;
  if (i < N) dinv[i] = rsqrtf((float)(rowptr[i + 1] - rowptr[i]));
}

// ------------- weight pack: WT[c][k] = bf16(W[k][c]), zero-pad c>=C -------------
__global__ void k_packw(const void* W, bf16* WT, int K, int C, int Cp, const int* flags){
  int f32 = flags[0];
  int idx = blockIdx.x * blockDim.x + threadIdx.x;
  if (idx >= Cp * K) return;
  int c = idx / K;
  int k = idx - c * K;
  WT[idx] = (c < C) ? f2b(ldp(W, (long long)k * C + c, f32)) : f2b(0.f);
}

// ------------- MFMA GEMM: out[N,C] = act(in[N,K] @ W[K,C] (+bias)) -------------
// Requires K % 32 == 0, WT packed [Cp][K] bf16 (Cp mult of 64, zero-padded).
// Block: 256 thr = 4 waves; wave covers 16 rows x 64 cols. No LDS.
// A-frag: A[m=lane&15][k=quad*8+j] -> 16B contiguous from row-major in.
// B-frag: B[k=quad*8+j][n=lane&15] -> 16B contiguous from WT row.
// C/D: col=lane&15, row=quad*4+reg.
__global__ __launch_bounds__(256) void k_gemm_mfma(
    const void* in, int ik, const bf16* WT, const void* bias,
    float* outf, bf16* outb, int N, int K, int C, int act, const int* flags)
{
  int f32 = flags[0];
  int use_b16 = (ik == 1) || (ik == 2 && !f32);
  int t = threadIdx.x;
  int wave = t >> 6, lane = t & 63;
  int quad = lane >> 4, l15 = lane & 15;
  int mbase = blockIdx.x * 64 + wave * 16;
  int c0 = blockIdx.y * 64;
  f32x4 acc[4];
#pragma unroll
  for (int j = 0; j < 4; ++j) acc[j] = (f32x4){0.f, 0.f, 0.f, 0.f};

  int m = mbase + l15; if (m > N - 1) m = N - 1;

  for (int k0 = 0; k0 < K; k0 += 32){
    int ka = k0 + quad * 8;
    short8 af;
    if (use_b16){
      af = *(const short8*)((const bf16*)in + (size_t)m * K + ka);
    } else {
      const float* p = (const float*)in + (size_t)m * K + ka;
      float4 v0 = *(const float4*)p;
      float4 v1 = *(const float4*)(p + 4);
      af[0] = f2bs(v0.x); af[1] = f2bs(v0.y); af[2] = f2bs(v0.z); af[3] = f2bs(v0.w);
      af[4] = f2bs(v1.x); af[5] = f2bs(v1.y); af[6] = f2bs(v1.z); af[7] = f2bs(v1.w);
    }
#pragma unroll
    for (int j = 0; j < 4; ++j){
      short8 bv = *(const short8*)(WT + (size_t)(c0 + 16 * j + l15) * K + ka);
      acc[j] = __builtin_amdgcn_mfma_f32_16x16x32_bf16(af, bv, acc[j], 0, 0, 0);
    }
  }
  // epilogue
#pragma unroll
  for (int j = 0; j < 4; ++j){
    int c = c0 + 16 * j + l15;
    if (c >= C) continue;
    float bi = bias ? ldp(bias, c, f32) : 0.f;
#pragma unroll
    for (int r = 0; r < 4; ++r){
      int n = mbase + quad * 4 + r;
      if (n >= N) continue;
      float y = acc[j][r] + bi;
      if (act == 1) y = fmaxf(y, 0.f) + log1pf(expf(-fabsf(y)));
      size_t o = (size_t)n * C + c;
      if (outb) outb[o] = f2b(y); else outf[o] = y;
    }
  }
}

// ------------- fallback tiled GEMM (R10-proven) for K%32!=0 -------------
__global__ __launch_bounds__(256) void k_gemm64(
    const void* in, int ik, const void* W, const void* bias,
    float* outf, bf16* outb, int N, int K, int C, int act, const int* flags)
{
  __shared__ float As[16][65];
  __shared__ float Ws[16][64];
  int f32 = flags[0];
  int use_b16 = (ik == 1) || (ik == 2 && !f32);
  int n0 = blockIdx.x * 64;
  int c0 = blockIdx.y * 64;
  int t = threadIdx.x;
  int tx = t & 15, ty = t >> 4;
  float acc[4][4];
#pragma unroll
  for (int i = 0; i < 4; ++i)
#pragma unroll
    for (int j = 0; j < 4; ++j) acc[i][j] = 0.f;
  int an = t >> 2;
  int ak = (t & 3) * 4;
  int wk = t >> 4;
  int wc = (t & 15) * 4;
  for (int k0 = 0; k0 < K; k0 += 16){
    {
      int n = n0 + an;
      float v0 = 0.f, v1 = 0.f, v2 = 0.f, v3 = 0.f;
      if (n < N){
        if (use_b16){
          const bf16* p = (const bf16*)in + (size_t)n * K + k0 + ak;
          v0 = b2f(p[0]); v1 = b2f(p[1]); v2 = b2f(p[2]); v3 = b2f(p[3]);
        } else {
          const float4 v4 = *(const float4*)((const float*)in + (size_t)n * K + k0 + ak);
          v0 = v4.x; v1 = v4.y; v2 = v4.z; v3 = v4.w;
        }
      }
      As[ak + 0][an] = v0; As[ak + 1][an] = v1;
      As[ak + 2][an] = v2; As[ak + 3][an] = v3;
    }
    {
      long long base = (long long)(k0 + wk) * C + c0;
#pragma unroll
      for (int j = 0; j < 4; ++j){
        int c = c0 + wc + j;
        Ws[wk][wc + j] = (c < C) ? ldp(W, base + wc + j, f32) : 0.f;
      }
    }
    __syncthreads();
#pragma unroll
    for (int k = 0; k < 16; ++k){
      float a0 = As[k][ty * 4 + 0], a1 = As[k][ty * 4 + 1];
      float a2 = As[k][ty * 4 + 2], a3 = As[k][ty * 4 + 3];
      float w0 = Ws[k][tx * 4 + 0], w1 = Ws[k][tx * 4 + 1];
      float w2 = Ws[k][tx * 4 + 2], w3 = Ws[k][tx * 4 + 3];
      acc[0][0] = fmaf(a0, w0, acc[0][0]); acc[0][1] = fmaf(a0, w1, acc[0][1]);
      acc[0][2] = fmaf(a0, w2, acc[0][2]); acc[0][3] = fmaf(a0, w3, acc[0][3]);
      acc[1][0] = fmaf(a1, w0, acc[1][0]); acc[1][1] = fmaf(a1, w1, acc[1][1]);
      acc[1][2] = fmaf(a1, w2, acc[1][2]); acc[1][3] = fmaf(a1, w3, acc[1][3]);
      acc[2][0] = fmaf(a2, w0, acc[2][0]); acc[2][1] = fmaf(a2, w1, acc[2][1]);
      acc[2][2] = fmaf(a2, w2, acc[2][2]); acc[2][3] = fmaf(a2, w3, acc[2][3]);
      acc[3][0] = fmaf(a3, w0, acc[3][0]); acc[3][1] = fmaf(a3, w1, acc[3][1]);
      acc[3][2] = fmaf(a3, w2, acc[3][2]); acc[3][3] = fmaf(a3, w3, acc[3][3]);
    }
    __syncthreads();
  }
#pragma unroll
  for (int i = 0; i < 4; ++i){
    int n = n0 + ty * 4 + i;
    if (n >= N) continue;
#pragma unroll
    for (int j = 0; j < 4; ++j){
      int c = c0 + tx * 4 + j;
      if (c >= C) continue;
      float y = acc[i][j];
      if (bias) y += ldp(bias, c, f32);
      if (act == 1) y = fmaxf(y, 0.f) + log1pf(expf(-fabsf(y)));
      size_t o = (size_t)n * C + c;
      if (outb) outb[o] = f2b(y); else outf[o] = y;
    }
  }
}

// ------------- GCN aggregate via CSR (h bf16, packed bf16x2 loads) -------------
__global__ __launch_bounds__(256) void k_gcn_csr(
    const int* rowptr, const unsigned short* colu, const bf16* h,
    const float* dinv, const void* bias, float* out, int N, int C,
    const int* flags)
{
  int f32 = flags[0];
  int wid = (blockIdx.x * 256 + threadIdx.x) >> 6;
  int lane = threadIdx.x & 63;
  if (wid >= N) return;
  int i0 = rowptr[wid], i1 = rowptr[wid + 1];
  float dr = dinv[wid];
  if (C == 128){
    int coff = lane << 1;
    float ax = 0.f, ay = 0.f, bx = 0.f, by = 0.f;
    int i = i0;
    for (; i + 1 < i1; i += 2){
      int s0 = colu[i], s1 = colu[i + 1];
      bf162 v0 = *(const bf162*)(h + (size_t)s0 * 128 + coff);
      bf162 v1 = *(const bf162*)(h + (size_t)s1 * 128 + coff);
      float f0 = dinv[s0], f1 = dinv[s1];
      ax = fmaf(f0, b2f(v0.x), ax); ay = fmaf(f0, b2f(v0.y), ay);
      bx = fmaf(f1, b2f(v1.x), bx); by = fmaf(f1, b2f(v1.y), by);
    }
    if (i < i1){
      int s0 = colu[i];
      bf162 v0 = *(const bf162*)(h + (size_t)s0 * 128 + coff);
      float f0 = dinv[s0];
      ax = fmaf(f0, b2f(v0.x), ax); ay = fmaf(f0, b2f(v0.y), ay);
    }
    out[(size_t)wid * 128 + coff]     = (ax + bx) * dr + ldp(bias, coff, f32);
    out[(size_t)wid * 128 + coff + 1] = (ay + by) * dr + ldp(bias, coff + 1, f32);
  } else { // C == 64
    int half = lane >> 5, hl = lane & 31;
    int coff = hl << 1;
    float ax = 0.f, ay = 0.f;
    int i = i0;
    for (; i + 1 < i1; i += 2){
      int s = colu[i + half];
      bf162 v = *(const bf162*)(h + (size_t)s * 64 + coff);
      float f = dinv[s];
      ax = fmaf(f, b2f(v.x), ax); ay = fmaf(f, b2f(v.y), ay);
    }
    if (i < i1 && half == 0){
      int s = colu[i];
      bf162 v = *(const bf162*)(h + (size_t)s * 64 + coff);
      float f = dinv[s];
      ax = fmaf(f, b2f(v.x), ax); ay = fmaf(f, b2f(v.y), ay);
    }
    ax += __shfl_xor(ax, 32);
    ay += __shfl_xor(ay, 32);
    if (half == 0){
      out[(size_t)wid * 64 + coff]     = ax * dr + ldp(bias, coff, f32);
      out[(size_t)wid * 64 + coff + 1] = ay * dr + ldp(bias, coff + 1, f32);
    }
  }
}

// ------------- GAT attention dots (hx stored bf16) -------------
__global__ void k_attn_dots(const bf16* hx, int C, const void* aw_s, const void* aw_d,
                            float* as_, float* ad_, int N, const int* flags)
{
  int f32 = flags[0];
  long long gtid = (long long)blockIdx.x * blockDim.x + threadIdx.x;
  int wave = (int)(gtid >> 6);
  int lane = threadIdx.x & 63;
  if (wave >= N * HEADS) return;
  int n = wave / HEADS, h = wave - n * HEADS;
  int HC = HEADS * C;
  float s0 = 0.f, s1 = 0.f;
  for (int c = lane; c < C; c += 64){
    float v = b2f(hx[(size_t)n * HC + h * C + c]);
    s0 += v * ldp(aw_s, h * C + c, f32);
    s1 += v * ldp(aw_d, h * C + c, f32);
  }
  for (int off = 32; off > 0; off >>= 1){
    s0 += __shfl_down(s0, off);
    s1 += __shfl_down(s1, off);
  }
  if (lane == 0){ as_[wave] = s0; ad_[wave] = s1; }
}

// ------------- per-row softmax -> per-edge weights ALPH[slot][5] (1/H folded) -------------
__global__ __launch_bounds__(256) void k_gat_alpha(
    const int* rowptr, const unsigned short* colu,
    const float* as_, const float* ad_, float* alph, int N)
{
  int wid = (blockIdx.x * 256 + threadIdx.x) >> 6;
  int lane = threadIdx.x & 63;
  if (wid >= N) return;
  int i0 = rowptr[wid], i1 = rowptr[wid + 1];
  float adr[HEADS];
#pragma unroll
  for (int h = 0; h < HEADS; ++h) adr[h] = ad_[wid * HEADS + h];
  float m[HEADS];
#pragma unroll
  for (int h = 0; h < HEADS; ++h) m[h] = -INFINITY;
  for (int i = i0 + lane; i < i1; i += 64){
    int s = colu[i];
#pragma unroll
    for (int h = 0; h < HEADS; ++h){
      float e = lrelu(as_[s * HEADS + h] + adr[h], 0.2f);
      m[h] = fmaxf(m[h], e);
    }
  }
#pragma unroll
  for (int h = 0; h < HEADS; ++h)
    for (int o = 32; o > 0; o >>= 1) m[h] = fmaxf(m[h], __shfl_xor(m[h], o));
  float den[HEADS];
#pragma unroll
  for (int h = 0; h < HEADS; ++h) den[h] = 0.f;
  for (int i = i0 + lane; i < i1; i += 64){
    int s = colu[i];
#pragma unroll
    for (int h = 0; h < HEADS; ++h){
      float e = lrelu(as_[s * HEADS + h] + adr[h], 0.2f);
      den[h] += expf(e - m[h]);
    }
  }
#pragma unroll
  for (int h = 0; h < HEADS; ++h){
    for (int o = 32; o > 0; o >>= 1) den[h] += __shfl_xor(den[h], o);
    den[h] = 1.f / (den[h] * (float)HEADS);
  }
  int tot = (i1 - i0) * HEADS;
  for (int idx = lane; idx < tot; idx += 64){
    int sl = idx / HEADS;
    int h = idx - sl * HEADS;
    int i = i0 + sl;
    int s = colu[i];
    float e = lrelu(as_[s * HEADS + h] + adr[h], 0.2f);
    alph[(size_t)i * HEADS + h] = expf(e - m[h]) * den[h];
  }
}

// ------------- fused GAT gather + bias + BN + leaky (+skip) -------------
__global__ __launch_bounds__(256) void k_gat_csr(
    const int* rowptr, const unsigned short* colu, const bf16* hx,
    const float* alph, int N, int C,
    const void* gb, const void* g, const void* bb, const void* bm, const void* bv,
    const float* skip, float* xout, const int* flags)
{
  int f32 = flags[0];
  int wid = (blockIdx.x * 256 + threadIdx.x) >> 6;
  int lane = threadIdx.x & 63;
  if (wid >= N) return;
  int i0 = rowptr[wid], i1 = rowptr[wid + 1];
  int HC = HEADS * C;
  if (C == 128){
    int coff = lane << 1;
    float ax = 0.f, ay = 0.f, bx = 0.f, by = 0.f;
    int i = i0;
    for (; i + 1 < i1; i += 2){
      int s0 = colu[i], s1 = colu[i + 1];
      const bf162* r0 = (const bf162*)(hx + (size_t)s0 * HC + coff);
      const bf162* r1 = (const bf162*)(hx + (size_t)s1 * HC + coff);
      const float* a0 = alph + (size_t)i * HEADS;
      const float* a1 = a0 + HEADS;
#pragma unroll
      for (int h = 0; h < HEADS; ++h){
        bf162 v0 = r0[h * 64];
        bf162 v1 = r1[h * 64];
        ax = fmaf(a0[h], b2f(v0.x), ax); ay = fmaf(a0[h], b2f(v0.y), ay);
        bx = fmaf(a1[h], b2f(v1.x), bx); by = fmaf(a1[h], b2f(v1.y), by);
      }
    }
    if (i < i1){
      int s0 = colu[i];
      const bf162* r0 = (const bf162*)(hx + (size_t)s0 * HC + coff);
      const float* a0 = alph + (size_t)i * HEADS;
#pragma unroll
      for (int h = 0; h < HEADS; ++h){
        bf162 v0 = r0[h * 64];
        ax = fmaf(a0[h], b2f(v0.x), ax); ay = fmaf(a0[h], b2f(v0.y), ay);
      }
    }
#pragma unroll
    for (int j = 0; j < 2; ++j){
      int c = coff + j;
      float y = (j ? (ay + by) : (ax + bx)) + ldp(gb, c, f32);
      y = (y - ldp(bm, c, f32)) * rsqrtf(ldp(bv, c, f32) + 1e-5f) * ldp(g, c, f32) + ldp(bb, c, f32);
      y = lrelu(y, 0.01f);
      if (skip) y += skip[(size_t)wid * C + c];
      xout[(size_t)wid * C + c] = y;
    }
  } else { // C == 64
    int half = lane >> 5, hl = lane & 31;
    int coff = hl << 1;
    float ax = 0.f, ay = 0.f;
    int i = i0;
    for (; i + 1 < i1; i += 2){
      int s = colu[i + half];
      const bf162* r = (const bf162*)(hx + (size_t)s * HC + coff);
      const float* a = alph + (size_t)(i + half) * HEADS;
#pragma unroll
      for (int h = 0; h < HEADS; ++h){
        bf162 v = r[h * 32];
        ax = fmaf(a[h], b2f(v.x), ax); ay = fmaf(a[h], b2f(v.y), ay);
      }
    }
    if (i < i1 && half == 0){
      int s = colu[i];
      const bf162* r = (const bf162*)(hx + (size_t)s * HC + coff);
      const float* a = alph + (size_t)i * HEADS;
#pragma unroll
      for (int h = 0; h < HEADS; ++h){
        bf162 v = r[h * 32];
        ax = fmaf(a[h], b2f(v.x), ax); ay = fmaf(a[h], b2f(v.y), ay);
      }
    }
    ax += __shfl_xor(ax, 32);
    ay += __shfl_xor(ay, 32);
    if (half == 0){
#pragma unroll
      for (int j = 0; j < 2; ++j){
        int c = coff + j;
        float y = (j ? ay : ax) + ldp(gb, c, f32);
        y = (y - ldp(bm, c, f32)) * rsqrtf(ldp(bv, c, f32) + 1e-5f) * ldp(g, c, f32) + ldp(bb, c, f32);
        y = lrelu(y, 0.01f);
        if (skip) y += skip[(size_t)wid * C + c];
        xout[(size_t)wid * C + c] = y;
      }
    }
  }
}

// y = lrelu01(bn(agg)) -> out fp32 (bn0 after stage A)
__global__ void k_postgat(const float* agg, const void* g, const void* b,
                          const void* m, const void* v, float* out,
                          long long total, int cmask, const int* flags)
{
  int f32 = flags[0];
  long long i = (long long)blockIdx.x * blockDim.x + threadIdx.x;
  if (i >= total) return;
  int c = (int)(i & cmask);
  float y = agg[i];
  y = (y - ldp(m, c, f32)) * rsqrtf(ldp(v, c, f32) + 1e-5f) * ldp(g, c, f32) + ldp(b, c, f32);
  y = lrelu(y, 0.01f);
  out[i] = y;
}

__global__ void k_concat(const float* x, const float* x2, void* o, int N, const int* flags)
{
  long long i = (long long)blockIdx.x * blockDim.x + threadIdx.x;
  if (i >= (long long)N * 192) return;
  int n = (int)(i / 192), c = (int)(i - (long long)n * 192);
  float v = (c < 128) ? x[(size_t)n * 128 + c] : x2[(size_t)n * 64 + (c - 128)];
  if (flags[0]) ((float*)o)[i] = v; else ((bf16*)o)[i] = f2b(v);
}

__global__ void k_final(const float* in, const void* w, const void* b, void* o,
                        int N, const int* flags)
{
  int f32 = flags[0];
  int n = blockIdx.x * blockDim.x + threadIdx.x;
  if (n >= N) return;
  float acc = ldp(b, 0, f32);
#pragma unroll
  for (int k = 0; k < 24; ++k) acc = fmaf(in[(size_t)n * 24 + k], ldp(w, k, f32), acc);
  float p = 1.f / (1.f + expf(-acc));
  long long o_i = (long long)N * 192 + n;
  if (f32) ((float*)o)[o_i] = p; else ((bf16*)o)[o_i] = f2b(p);
}

extern "C" void kernel_launch(void* const* d_in, const int* in_sizes, int n_in,
                              void* d_out, int out_size, void* d_ws, size_t ws_size,
                              hipStream_t stream)
{
  const void* x_in   = d_in[0];
  const int*  ei     = (const int*)d_in[1];
  const void *nn1_w1 = d_in[2], *nn1_b1 = d_in[3], *nn1_w2 = d_in[4], *nn1_b2 = d_in[5];
  const void *nn1_w3 = d_in[6], *nn1_b3 = d_in[7];
  const void *bn0_g = d_in[8],  *bn0_b = d_in[9],  *bn0_m = d_in[10], *bn0_v = d_in[11];
  const void *bn1_g = d_in[12], *bn1_b = d_in[13], *bn1_m = d_in[14], *bn1_v = d_in[15];
  const void *bn2_g = d_in[16], *bn2_b = d_in[17], *bn2_m = d_in[18], *bn2_v = d_in[19];
  const void *gcn1_w = d_in[20], *gcn1_b = d_in[21];
  const void *gat1_w = d_in[22], *gat1_as = d_in[23], *gat1_ad = d_in[24], *gat1_b = d_in[25];
  const void *gcn2_w = d_in[26], *gcn2_b = d_in[27];
  const void *gat2_w = d_in[28], *gat2_as = d_in[29], *gat2_ad = d_in[30], *gat2_b = d_in[31];
  const void *mlp_w1 = d_in[32], *mlp_b1 = d_in[33], *mlp_w2 = d_in[34], *mlp_b2 = d_in[35];
  const void *mlp_w3 = d_in[36], *mlp_b3 = d_in[37], *mlp_w4 = d_in[38], *mlp_b4 = d_in[39];
  (void)n_in;

  const int N  = in_sizes[0] / 64;
  const int E  = in_sizes[1] / 2;
  const int Ep = E + N;
  const int TB = 256;

  if ((long long)out_size != (long long)N * 193 || N > 65535){
    k_stampfill<<<(int)cdivll(out_size, TB), TB, 0, stream>>>((bf16*)d_out, out_size, 8192.f);
    return;
  }
  size_t need = 16 + sizeof(float) * ((size_t)N * (128 * 3 + 1 + 4 * HEADS)) + 2ull * (size_t)N * 640;
  if (ws_size < need + 256){
    k_stampfill<<<(int)cdivll(out_size, TB), TB, 0, stream>>>((bf16*)d_out, out_size, 1024.f);
    return;
  }

  // ws layout: flags | X | A | B | DINV | AS | AD | rowptr | colu(u16) | HX(bf16)
  char* wsb = (char*)d_ws;
  int*   FLAGS = (int*)wsb;
  float* X    = (float*)(wsb + 16);
  float* A    = X + (size_t)N * 128;
  float* B    = A + (size_t)N * 128;
  float* DINV = B + (size_t)N * 128;
  float* AS   = DINV + N;
  float* AD   = AS + (size_t)N * HEADS;
  int*   ROWP = (int*)(AD + (size_t)N * HEADS);
  unsigned short* COLU = (unsigned short*)(ROWP + N + 1);
  bf16*  HX   = (bf16*)(COLU + ((Ep + 7) & ~7));
  float* X2   = A;           // gat2 output lives in A
  float* ALPH = B;           // aliases B (dead once gat gemm consumed B)
  int* CNT = (int*)AS;
  int* CUR = CNT + N;

  k_detect<<<1, 256, 0, stream>>>((const unsigned short*)x_in, ei, FLAGS);

  // ---- CSR build ----
  k_zeroi<<<(int)cdivll(2 * N, TB), TB, 0, stream>>>(CNT, 2 * N);
  k_hist<<<(int)cdivll(Ep, TB), TB, 0, stream>>>(ei, E, N, CNT, FLAGS);
  k_scan<<<1, 256, 0, stream>>>(CNT, ROWP, N);
  k_scatter<<<(int)cdivll(Ep, TB), TB, 0, stream>>>(ei, E, N, ROWP, CUR, COLU, FLAGS);
  k_dinv<<<(int)cdivll(N, TB), TB, 0, stream>>>(ROWP, DINV, N);

  // MFMA gemm with per-call WT scratch (free buffer at that point in the schedule)
  auto gemm = [&](const void* in, int ik, const void* W, const void* bias,
                  float* of, bf16* ob, int K, int C, int act, void* scratch){
    int Cp = (int)((C + 63) / 64) * 64;
    bf16* wt = (bf16*)scratch;
    k_packw<<<(int)cdivll((long long)Cp * K, TB), TB, 0, stream>>>(W, wt, K, C, Cp, FLAGS);
    dim3 g((unsigned)cdivll(N, 64), (unsigned)(Cp / 64));
    k_gemm_mfma<<<g, 256, 0, stream>>>(in, ik, wt, bias, of, ob, N, K, C, act, FLAGS);
  };
  int rowsg = (int)cdivll(N, 4);

  // ---- stage A: nn1 MLP + bn0 + leaky ----
  gemm(x_in, 2, nn1_w1, nn1_b1, A, nullptr, 64, 128, 1, B);
  gemm(A, 0, nn1_w2, nn1_b2, B, nullptr, 128, 64, 1, X);
  gemm(B, 0, nn1_w3, nn1_b3, A, nullptr, 64, 128, 0, X);
  k_postgat<<<(int)cdivll((long long)N * 128, TB), TB, 0, stream>>>(
      A, bn0_g, bn0_b, bn0_m, bn0_v, X, (long long)N * 128, 127, FLAGS);

  // ---- GCN1 ----
  gemm(X, 0, gcn1_w, nullptr, nullptr, HX, 128, 128, 0, A);
  k_gcn_csr<<<rowsg, 256, 0, stream>>>(ROWP, COLU, HX, DINV, gcn1_b, B, N, 128, FLAGS);

  // ---- GAT1 (fused gather+bias+bn1+leaky+skip -> X) ----
  gemm(B, 0, gat1_w, nullptr, nullptr, HX, 128, 640, 0, A);
  k_attn_dots<<<(int)cdivll((long long)N * HEADS * 64, TB), TB, 0, stream>>>(HX, 128, gat1_as, gat1_ad, AS, AD, N, FLAGS);
  k_gat_alpha<<<rowsg, 256, 0, stream>>>(ROWP, COLU, AS, AD, ALPH, N);
  k_gat_csr<<<rowsg, 256, 0, stream>>>(ROWP, COLU, HX, ALPH, N, 128,
      gat1_b, bn1_g, bn1_b, bn1_m, bn1_v, X, X, FLAGS);

  // ---- GCN2 ----
  gemm(X, 0, gcn2_w, nullptr, nullptr, HX, 128, 64, 0, A);
  k_gcn_csr<<<rowsg, 256, 0, stream>>>(ROWP, COLU, HX, DINV, gcn2_b, B, N, 64, FLAGS);

  // ---- GAT2 (fused -> X2) ----
  gemm(B, 0, gat2_w, nullptr, nullptr, HX, 64, 320, 0, A);
  k_attn_dots<<<(int)cdivll((long long)N * HEADS * 64, TB), TB, 0, stream>>>(HX, 64, gat2_as, gat2_ad, AS, AD, N, FLAGS);
  k_gat_alpha<<<rowsg, 256, 0, stream>>>(ROWP, COLU, AS, AD, ALPH, N);
  k_gat_csr<<<rowsg, 256, 0, stream>>>(ROWP, COLU, HX, ALPH, N, 64,
      gat2_b, bn2_g, bn2_b, bn2_m, bn2_v, nullptr, X2, FLAGS);

  // ---- concat -> d_out ----
  k_concat<<<(int)cdivll((long long)N * 192, TB), TB, 0, stream>>>(X, X2, d_out, N, FLAGS);

  // ---- node_pred MLP ----
  gemm(d_out, 2, mlp_w1, mlp_b1, A, nullptr, 192, 96, 1, B);
  gemm(A, 0, mlp_w2, mlp_b2, B, nullptr, 96, 48, 1, X);
  { // K=48 not a multiple of 32 -> fallback tiled kernel
    dim3 g((unsigned)cdivll(N, 64), 1);
    k_gemm64<<<g, 256, 0, stream>>>(B, 0, mlp_w3, mlp_b3, A, nullptr, N, 48, 24, 1, FLAGS);
  }
  k_final<<<(int)cdivll(N, TB), TB, 0, stream>>>(A, mlp_w4, mlp_b4, d_out, N, FLAGS);
}

// Round 13
// 626.712 us; speedup vs baseline: 1.2658x; 1.0617x over previous
//
#include <hip/hip_runtime.h>
#include <hip/hip_bf16.h>
#include <math.h>
#include <stdint.h>

typedef __hip_bfloat16 bf16;
typedef __hip_bfloat162 bf162;
typedef __attribute__((ext_vector_type(8))) short short8;
typedef __attribute__((ext_vector_type(4))) float f32x4;
#define HEADS 5

static inline long long cdivll(long long a, long long b){ return (a + b - 1) / b; }

__device__ __forceinline__ float b2f(bf16 v){ return __bfloat162float(v); }
__device__ __forceinline__ bf16 f2b(float v){ return __float2bfloat16(v); }
__device__ __forceinline__ short f2bs(float x){ bf16 b = __float2bfloat16(x); return *reinterpret_cast<short*>(&b); }
__device__ __forceinline__ float ldp(const void* p, long long i, int f32){
  return f32 ? ((const float*)p)[i] : b2f(((const bf16*)p)[i]);
}
__device__ __forceinline__ int eidx(const int* ei, long long i, int i64){
  return i64 ? ei[2 * i] : ei[i];
}
__device__ __forceinline__ float lrelu(float x, float a){ return x >= 0.f ? x : a * x; }

// ---------------- runtime dtype detection ----------------
__global__ void k_detect(const unsigned short* xh, const int* ei, int* flags){
  __shared__ int r0[256], r1[256];
  int t = threadIdx.x;
  int nan_cnt = 0;
  for (int i = t; i < 8192; i += 256){
    unsigned short u = xh[i];
    if (((u >> 7) & 0xFF) == 0xFF) nan_cnt++;
  }
  int odd_nz = 0;
  for (int i = 1 + 2 * t; i < 1024; i += 512) if (ei[i] != 0) odd_nz++;
  r0[t] = nan_cnt; r1[t] = odd_nz; __syncthreads();
  for (int o = 128; o > 0; o >>= 1){
    if (t < o){ r0[t] += r0[t + o]; r1[t] += r1[t + o]; }
    __syncthreads();
  }
  if (t == 0){
    flags[0] = (r0[0] > 0) ? 1 : 0;
    flags[1] = (r1[0] == 0) ? 1 : 0;
  }
}

__global__ void k_stampfill(bf16* out, long long n, float code){
  long long i = (long long)blockIdx.x * blockDim.x + threadIdx.x;
  if (i < n) out[i] = f2b(i == 0 ? code : 0.f);
}

// ---------------- CSR build ----------------
__global__ void k_zeroi(int* p, int n){
  int i = blockIdx.x * blockDim.x + threadIdx.x;
  if (i < n) p[i] = 0;
}
__global__ void k_hist(const int* ei, int E, int N, int* counts, const int* flags){
  int i64 = flags[1];
  int e = blockIdx.x * blockDim.x + threadIdx.x;
  if (e >= E + N) return;
  int d = (e < E) ? eidx(ei, (long long)E + e, i64) : (e - E);
  atomicAdd(&counts[d], 1);
}
__global__ void k_scan(const int* counts, int* rowptr, int N){
  __shared__ int sums[256];
  int t = threadIdx.x;
  int chunk = (N + 255) / 256;
  int start = t * chunk;
  int end = start + chunk; if (end > N) end = N;
  int s = 0;
  for (int i = start; i < end; ++i) s += counts[i];
  sums[t] = s; __syncthreads();
  for (int o = 1; o < 256; o <<= 1){
    int v = (t >= o) ? sums[t - o] : 0;
    __syncthreads();
    sums[t] += v;
    __syncthreads();
  }
  int run = (t == 0) ? 0 : sums[t - 1];
  for (int i = start; i < end; ++i){ rowptr[i] = run; run += counts[i]; }
  if (t == 0) rowptr[N] = sums[255];
}
__global__ void k_scatter(const int* ei, int E, int N, const int* rowptr, int* cursor,
                          unsigned short* colu, const int* flags){
  int i64 = flags[1];
  int e = blockIdx.x * blockDim.x + threadIdx.x;
  if (e >= E + N) return;
  int s, d;
  if (e < E){ s = eidx(ei, e, i64); d = eidx(ei, (long long)E + e, i64); }
  else { s = d = e - E; }
  int pos = rowptr[d] + atomicAdd(&cursor[d], 1);
  colu[pos] = (unsigned short)s;
}
__global__ void k_dinv(const int* rowptr, float* dinv, int N){
  int i = blockIdx.x * blockDim.x + threadIdx.x;
  if (i < N) dinv[i] = rsqrtf((float)(rowptr[i + 1] - rowptr[i]));
}

// ------------- pack ALL weights -> WT arena [c][k], zero-padded -------------
struct PackDesc { const void* W; int K, Kp, C, Cp, off; };
struct PackArgs { PackDesc d[10]; int total; };
__global__ void k_packall(PackArgs P, bf16* WTA, const int* flags){
  int f32 = flags[0];
  int idx = blockIdx.x * blockDim.x + threadIdx.x;
  if (idx >= P.total) return;
  int base = 0;
#pragma unroll
  for (int s = 0; s < 10; ++s){
    int sz = P.d[s].Kp * P.d[s].Cp;
    if (idx < base + sz){
      int local = idx - base;
      int c = local / P.d[s].Kp;
      int k = local - c * P.d[s].Kp;
      float v = (k < P.d[s].K && c < P.d[s].C)
              ? ldp(P.d[s].W, (long long)k * P.d[s].C + c, f32) : 0.f;
      WTA[P.d[s].off + local] = f2b(v);
      return;
    }
    base += sz;
  }
}

// ------------- MFMA GEMM: out[N,C] = act(in[N,Kp] @ WT^T (+bias)) -------------
// Kp % 32 == 0; in row stride == Kp; WT [Cp][Kp] bf16 zero-padded.
// mode: 0 none, 1 softplus, 2 bias+BN+leaky0.01. czero: zero-fill cols [C, czero).
__global__ __launch_bounds__(256) void k_gemm_mfma(
    const void* in, int ik, const bf16* WT, int Kp, const void* bias,
    float* outf, bf16* outb, int N, int C, int ldc, int czero, int mode,
    const void* bg, const void* bb, const void* bm, const void* bv,
    const int* flags)
{
  int f32 = flags[0];
  int use_b16 = (ik == 1) || (ik == 2 && !f32);
  int t = threadIdx.x;
  int wave = t >> 6, lane = t & 63;
  int quad = lane >> 4, l15 = lane & 15;
  int mbase = blockIdx.x * 64 + wave * 16;
  int c0 = blockIdx.y * 64;
  f32x4 acc[4];
#pragma unroll
  for (int j = 0; j < 4; ++j) acc[j] = (f32x4){0.f, 0.f, 0.f, 0.f};

  int m = mbase + l15; if (m > N - 1) m = N - 1;

  for (int k0 = 0; k0 < Kp; k0 += 32){
    int ka = k0 + quad * 8;
    short8 af;
    if (use_b16){
      af = *(const short8*)((const bf16*)in + (size_t)m * Kp + ka);
    } else {
      const float* p = (const float*)in + (size_t)m * Kp + ka;
      float4 v0 = *(const float4*)p;
      float4 v1 = *(const float4*)(p + 4);
      af[0] = f2bs(v0.x); af[1] = f2bs(v0.y); af[2] = f2bs(v0.z); af[3] = f2bs(v0.w);
      af[4] = f2bs(v1.x); af[5] = f2bs(v1.y); af[6] = f2bs(v1.z); af[7] = f2bs(v1.w);
    }
#pragma unroll
    for (int j = 0; j < 4; ++j){
      short8 bv = *(const short8*)(WT + (size_t)(c0 + 16 * j + l15) * Kp + ka);
      acc[j] = __builtin_amdgcn_mfma_f32_16x16x32_bf16(af, bv, acc[j], 0, 0, 0);
    }
  }
#pragma unroll
  for (int j = 0; j < 4; ++j){
    int c = c0 + 16 * j + l15;
    if (c < C){
      float bi = bias ? ldp(bias, c, f32) : 0.f;
      float g = 0.f, be = 0.f, mm = 0.f, iv = 0.f;
      if (mode == 2){
        g = ldp(bg, c, f32); be = ldp(bb, c, f32); mm = ldp(bm, c, f32);
        iv = rsqrtf(ldp(bv, c, f32) + 1e-5f);
      }
#pragma unroll
      for (int r = 0; r < 4; ++r){
        int n = mbase + quad * 4 + r;
        if (n >= N) continue;
        float y = acc[j][r] + bi;
        if (mode == 1) y = fmaxf(y, 0.f) + log1pf(expf(-fabsf(y)));
        else if (mode == 2){ y = (y - mm) * iv * g + be; y = lrelu(y, 0.01f); }
        size_t o = (size_t)n * ldc + c;
        if (outb) outb[o] = f2b(y); else outf[o] = y;
      }
    } else if (c < czero){
#pragma unroll
      for (int r = 0; r < 4; ++r){
        int n = mbase + quad * 4 + r;
        if (n >= N) continue;
        size_t o = (size_t)n * ldc + c;
        if (outb) outb[o] = f2b(0.f); else outf[o] = 0.f;
      }
    }
  }
}

// ------------- GCN aggregate via CSR (h bf16) -------------
__global__ __launch_bounds__(256) void k_gcn_csr(
    const int* rowptr, const unsigned short* colu, const bf16* h,
    const float* dinv, const void* bias, float* out, int N, int C,
    const int* flags)
{
  int f32 = flags[0];
  int wid = (blockIdx.x * 256 + threadIdx.x) >> 6;
  int lane = threadIdx.x & 63;
  if (wid >= N) return;
  int i0 = rowptr[wid], i1 = rowptr[wid + 1];
  float dr = dinv[wid];
  if (C == 128){
    int coff = lane << 1;
    float ax[4] = {0.f, 0.f, 0.f, 0.f}, ay[4] = {0.f, 0.f, 0.f, 0.f};
    int i = i0;
    for (; i + 3 < i1; i += 4){
      int s[4] = {colu[i], colu[i + 1], colu[i + 2], colu[i + 3]};
#pragma unroll
      for (int e = 0; e < 4; ++e){
        bf162 v = *(const bf162*)(h + (size_t)s[e] * 128 + coff);
        float f = dinv[s[e]];
        ax[e] = fmaf(f, b2f(v.x), ax[e]); ay[e] = fmaf(f, b2f(v.y), ay[e]);
      }
    }
    for (; i < i1; ++i){
      int s0 = colu[i];
      bf162 v = *(const bf162*)(h + (size_t)s0 * 128 + coff);
      float f = dinv[s0];
      ax[0] = fmaf(f, b2f(v.x), ax[0]); ay[0] = fmaf(f, b2f(v.y), ay[0]);
    }
    float sx = (ax[0] + ax[1]) + (ax[2] + ax[3]);
    float sy = (ay[0] + ay[1]) + (ay[2] + ay[3]);
    out[(size_t)wid * 128 + coff]     = sx * dr + ldp(bias, coff, f32);
    out[(size_t)wid * 128 + coff + 1] = sy * dr + ldp(bias, coff + 1, f32);
  } else { // C == 64
    int half = lane >> 5, hl = lane & 31;
    int coff = hl << 1;
    float ax = 0.f, ay = 0.f;
    int i = i0;
    for (; i + 1 < i1; i += 2){
      int s = colu[i + half];
      bf162 v = *(const bf162*)(h + (size_t)s * 64 + coff);
      float f = dinv[s];
      ax = fmaf(f, b2f(v.x), ax); ay = fmaf(f, b2f(v.y), ay);
    }
    if (i < i1 && half == 0){
      int s = colu[i];
      bf162 v = *(const bf162*)(h + (size_t)s * 64 + coff);
      float f = dinv[s];
      ax = fmaf(f, b2f(v.x), ax); ay = fmaf(f, b2f(v.y), ay);
    }
    ax += __shfl_xor(ax, 32);
    ay += __shfl_xor(ay, 32);
    if (half == 0){
      out[(size_t)wid * 64 + coff]     = ax * dr + ldp(bias, coff, f32);
      out[(size_t)wid * 64 + coff + 1] = ay * dr + ldp(bias, coff + 1, f32);
    }
  }
}

// ------------- GAT attention dots (hx stored bf16) -------------
__global__ void k_attn_dots(const bf16* hx, int C, const void* aw_s, const void* aw_d,
                            float* as_, float* ad_, int N, const int* flags)
{
  int f32 = flags[0];
  long long gtid = (long long)blockIdx.x * blockDim.x + threadIdx.x;
  int wave = (int)(gtid >> 6);
  int lane = threadIdx.x & 63;
  if (wave >= N * HEADS) return;
  int n = wave / HEADS, h = wave - n * HEADS;
  int HC = HEADS * C;
  float s0 = 0.f, s1 = 0.f;
  for (int c = lane; c < C; c += 64){
    float v = b2f(hx[(size_t)n * HC + h * C + c]);
    s0 += v * ldp(aw_s, h * C + c, f32);
    s1 += v * ldp(aw_d, h * C + c, f32);
  }
  for (int off = 32; off > 0; off >>= 1){
    s0 += __shfl_down(s0, off);
    s1 += __shfl_down(s1, off);
  }
  if (lane == 0){ as_[wave] = s0; ad_[wave] = s1; }
}

// ------------- per-row softmax -> per-edge weights ALPH[slot][5] (1/H folded) -------------
__global__ __launch_bounds__(256) void k_gat_alpha(
    const int* rowptr, const unsigned short* colu,
    const float* as_, const float* ad_, float* alph, int N)
{
  int wid = (blockIdx.x * 256 + threadIdx.x) >> 6;
  int lane = threadIdx.x & 63;
  if (wid >= N) return;
  int i0 = rowptr[wid], i1 = rowptr[wid + 1];
  float adr[HEADS];
#pragma unroll
  for (int h = 0; h < HEADS; ++h) adr[h] = ad_[wid * HEADS + h];
  float m[HEADS];
#pragma unroll
  for (int h = 0; h < HEADS; ++h) m[h] = -INFINITY;
  for (int i = i0 + lane; i < i1; i += 64){
    int s = colu[i];
#pragma unroll
    for (int h = 0; h < HEADS; ++h){
      float e = lrelu(as_[s * HEADS + h] + adr[h], 0.2f);
      m[h] = fmaxf(m[h], e);
    }
  }
#pragma unroll
  for (int h = 0; h < HEADS; ++h)
    for (int o = 32; o > 0; o >>= 1) m[h] = fmaxf(m[h], __shfl_xor(m[h], o));
  float den[HEADS];
#pragma unroll
  for (int h = 0; h < HEADS; ++h) den[h] = 0.f;
  for (int i = i0 + lane; i < i1; i += 64){
    int s = colu[i];
#pragma unroll
    for (int h = 0; h < HEADS; ++h){
      float e = lrelu(as_[s * HEADS + h] + adr[h], 0.2f);
      den[h] += expf(e - m[h]);
    }
  }
#pragma unroll
  for (int h = 0; h < HEADS; ++h){
    for (int o = 32; o > 0; o >>= 1) den[h] += __shfl_xor(den[h], o);
    den[h] = 1.f / (den[h] * (float)HEADS);
  }
  int tot = (i1 - i0) * HEADS;
  for (int idx = lane; idx < tot; idx += 64){
    int sl = idx / HEADS;
    int h = idx - sl * HEADS;
    int i = i0 + sl;
    int s = colu[i];
    float e = lrelu(as_[s * HEADS + h] + adr[h], 0.2f);
    alph[(size_t)i * HEADS + h] = expf(e - m[h]) * den[h];
  }
}

// ------------- fused GAT gather + bias + BN + leaky (+skip) -------------
__global__ __launch_bounds__(256) void k_gat_csr(
    const int* rowptr, const unsigned short* colu, const bf16* hx,
    const float* alph, int N, int C,
    const void* gb, const void* g, const void* bb, const void* bm, const void* bv,
    const float* skip, float* xout, const int* flags)
{
  int f32 = flags[0];
  int wid = (blockIdx.x * 256 + threadIdx.x) >> 6;
  int lane = threadIdx.x & 63;
  if (wid >= N) return;
  int i0 = rowptr[wid], i1 = rowptr[wid + 1];
  int HC = HEADS * C;
  if (C == 128){
    int coff = lane << 1;
    float ax[4] = {0.f, 0.f, 0.f, 0.f}, ay[4] = {0.f, 0.f, 0.f, 0.f};
    int i = i0;
    for (; i + 3 < i1; i += 4){
      int s[4] = {colu[i], colu[i + 1], colu[i + 2], colu[i + 3]};
      const float* a = alph + (size_t)i * HEADS;
#pragma unroll
      for (int e = 0; e < 4; ++e){
        const bf162* r = (const bf162*)(hx + (size_t)s[e] * HC + coff);
#pragma unroll
        for (int h = 0; h < HEADS; ++h){
          bf162 v = r[h * 64];
          float w = a[e * HEADS + h];
          ax[e] = fmaf(w, b2f(v.x), ax[e]); ay[e] = fmaf(w, b2f(v.y), ay[e]);
        }
      }
    }
    for (; i < i1; ++i){
      int s0 = colu[i];
      const bf162* r = (const bf162*)(hx + (size_t)s0 * HC + coff);
      const float* a = alph + (size_t)i * HEADS;
#pragma unroll
      for (int h = 0; h < HEADS; ++h){
        bf162 v = r[h * 64];
        ax[0] = fmaf(a[h], b2f(v.x), ax[0]); ay[0] = fmaf(a[h], b2f(v.y), ay[0]);
      }
    }
    float sx = (ax[0] + ax[1]) + (ax[2] + ax[3]);
    float sy = (ay[0] + ay[1]) + (ay[2] + ay[3]);
#pragma unroll
    for (int j = 0; j < 2; ++j){
      int c = coff + j;
      float y = (j ? sy : sx) + ldp(gb, c, f32);
      y = (y - ldp(bm, c, f32)) * rsqrtf(ldp(bv, c, f32) + 1e-5f) * ldp(g, c, f32) + ldp(bb, c, f32);
      y = lrelu(y, 0.01f);
      if (skip) y += skip[(size_t)wid * C + c];
      xout[(size_t)wid * C + c] = y;
    }
  } else { // C == 64
    int half = lane >> 5, hl = lane & 31;
    int coff = hl << 1;
    float ax = 0.f, ay = 0.f;
    int i = i0;
    for (; i + 1 < i1; i += 2){
      int s = colu[i + half];
      const bf162* r = (const bf162*)(hx + (size_t)s * HC + coff);
      const float* a = alph + (size_t)(i + half) * HEADS;
#pragma unroll
      for (int h = 0; h < HEADS; ++h){
        bf162 v = r[h * 32];
        ax = fmaf(a[h], b2f(v.x), ax); ay = fmaf(a[h], b2f(v.y), ay);
      }
    }
    if (i < i1 && half == 0){
      int s = colu[i];
      const bf162* r = (const bf162*)(hx + (size_t)s * HC + coff);
      const float* a = alph + (size_t)i * HEADS;
#pragma unroll
      for (int h = 0; h < HEADS; ++h){
        bf162 v = r[h * 32];
        ax = fmaf(a[h], b2f(v.x), ax); ay = fmaf(a[h], b2f(v.y), ay);
      }
    }
    ax += __shfl_xor(ax, 32);
    ay += __shfl_xor(ay, 32);
    if (half == 0){
#pragma unroll
      for (int j = 0; j < 2; ++j){
        int c = coff + j;
        float y = (j ? ay : ax) + ldp(gb, c, f32);
        y = (y - ldp(bm, c, f32)) * rsqrtf(ldp(bv, c, f32) + 1e-5f) * ldp(g, c, f32) + ldp(bb, c, f32);
        y = lrelu(y, 0.01f);
        if (skip) y += skip[(size_t)wid * C + c];
        xout[(size_t)wid * C + c] = y;
      }
    }
  }
}

__global__ void k_concat(const float* x, const float* x2, void* o, int N, const int* flags)
{
  long long i = (long long)blockIdx.x * blockDim.x + threadIdx.x;
  if (i >= (long long)N * 192) return;
  int n = (int)(i / 192), c = (int)(i - (long long)n * 192);
  float v = (c < 128) ? x[(size_t)n * 128 + c] : x2[(size_t)n * 64 + (c - 128)];
  if (flags[0]) ((float*)o)[i] = v; else ((bf16*)o)[i] = f2b(v);
}

__global__ void k_final(const float* in, const void* w, const void* b, void* o,
                        int N, const int* flags)
{
  int f32 = flags[0];
  int n = blockIdx.x * blockDim.x + threadIdx.x;
  if (n >= N) return;
  float acc = ldp(b, 0, f32);
#pragma unroll
  for (int k = 0; k < 24; ++k) acc = fmaf(in[(size_t)n * 24 + k], ldp(w, k, f32), acc);
  float p = 1.f / (1.f + expf(-acc));
  long long o_i = (long long)N * 192 + n;
  if (f32) ((float*)o)[o_i] = p; else ((bf16*)o)[o_i] = f2b(p);
}

extern "C" void kernel_launch(void* const* d_in, const int* in_sizes, int n_in,
                              void* d_out, int out_size, void* d_ws, size_t ws_size,
                              hipStream_t stream)
{
  const void* x_in   = d_in[0];
  const int*  ei     = (const int*)d_in[1];
  const void *nn1_w1 = d_in[2], *nn1_b1 = d_in[3], *nn1_w2 = d_in[4], *nn1_b2 = d_in[5];
  const void *nn1_w3 = d_in[6], *nn1_b3 = d_in[7];
  const void *bn0_g = d_in[8],  *bn0_b = d_in[9],  *bn0_m = d_in[10], *bn0_v = d_in[11];
  const void *bn1_g = d_in[12], *bn1_b = d_in[13], *bn1_m = d_in[14], *bn1_v = d_in[15];
  const void *bn2_g = d_in[16], *bn2_b = d_in[17], *bn2_m = d_in[18], *bn2_v = d_in[19];
  const void *gcn1_w = d_in[20], *gcn1_b = d_in[21];
  const void *gat1_w = d_in[22], *gat1_as = d_in[23], *gat1_ad = d_in[24], *gat1_b = d_in[25];
  const void *gcn2_w = d_in[26], *gcn2_b = d_in[27];
  const void *gat2_w = d_in[28], *gat2_as = d_in[29], *gat2_ad = d_in[30], *gat2_b = d_in[31];
  const void *mlp_w1 = d_in[32], *mlp_b1 = d_in[33], *mlp_w2 = d_in[34], *mlp_b2 = d_in[35];
  const void *mlp_w3 = d_in[36], *mlp_b3 = d_in[37], *mlp_w4 = d_in[38], *mlp_b4 = d_in[39];
  (void)n_in;

  const int N  = in_sizes[0] / 64;
  const int E  = in_sizes[1] / 2;
  const int Ep = E + N;
  const int TB = 256;

  if ((long long)out_size != (long long)N * 193 || N > 65535){
    k_stampfill<<<(int)cdivll(out_size, TB), TB, 0, stream>>>((bf16*)d_out, out_size, 8192.f);
    return;
  }
  size_t need = 2900ull * (size_t)N + 500000ull;  // R12 layout + 0.38 MB WT arena + align
  if (ws_size < need){
    k_stampfill<<<(int)cdivll(out_size, TB), TB, 0, stream>>>((bf16*)d_out, out_size, 1024.f);
    return;
  }

  // ws layout: flags | X | A | B | DINV | AS | AD | rowptr | colu(u16) | HX(bf16) | WTA(bf16)
  char* wsb = (char*)d_ws;
  int*   FLAGS = (int*)wsb;
  float* X    = (float*)(wsb + 16);
  float* A    = X + (size_t)N * 128;
  float* B    = A + (size_t)N * 128;
  float* DINV = B + (size_t)N * 128;
  float* AS   = DINV + N;
  float* AD   = AS + (size_t)N * HEADS;
  int*   ROWP = (int*)(AD + (size_t)N * HEADS);
  unsigned short* COLU = (unsigned short*)(ROWP + N + 1);
  bf16*  HX   = (bf16*)(COLU + ((Ep + 7) & ~7));
  bf16*  WTA  = (bf16*)(((uintptr_t)(HX + (size_t)N * 640) + 15) & ~(uintptr_t)15);
  float* X2   = A;           // gat2 output lives in A
  float* ALPH = B;           // aliases B (dead once gat gemm consumed B)
  int* CNT = (int*)AS;
  int* CUR = CNT + N;

  k_detect<<<1, 256, 0, stream>>>((const unsigned short*)x_in, ei, FLAGS);

  // ---- pack all weights (offsets in bf16 elements) ----
  PackArgs P;
  P.d[0] = {nn1_w1,  64, 64, 128, 128, 0};
  P.d[1] = {nn1_w2, 128,128,  64,  64, 8192};
  P.d[2] = {nn1_w3,  64, 64, 128, 128, 16384};
  P.d[3] = {gcn1_w, 128,128, 128, 128, 24576};
  P.d[4] = {gat1_w, 128,128, 640, 640, 40960};
  P.d[5] = {gcn2_w, 128,128,  64,  64, 122880};
  P.d[6] = {gat2_w,  64, 64, 320, 320, 131072};
  P.d[7] = {mlp_w1, 192,192,  96, 128, 151552};
  P.d[8] = {mlp_w2,  96, 96,  48,  64, 176128};
  P.d[9] = {mlp_w3,  48, 64,  24,  64, 182272};
  P.total = 186368;
  k_packall<<<(int)cdivll(P.total, TB), TB, 0, stream>>>(P, WTA, FLAGS);

  // ---- CSR build ----
  k_zeroi<<<(int)cdivll(2 * N, TB), TB, 0, stream>>>(CNT, 2 * N);
  k_hist<<<(int)cdivll(Ep, TB), TB, 0, stream>>>(ei, E, N, CNT, FLAGS);
  k_scan<<<1, 256, 0, stream>>>(CNT, ROWP, N);
  k_scatter<<<(int)cdivll(Ep, TB), TB, 0, stream>>>(ei, E, N, ROWP, CUR, COLU, FLAGS);
  k_dinv<<<(int)cdivll(N, TB), TB, 0, stream>>>(ROWP, DINV, N);

  const void* nv = nullptr;
  auto gemm = [&](const void* in, int ik, int off, int Kp, const void* bias,
                  float* of, bf16* ob, int C, int Cp, int ldc, int czero, int mode,
                  const void* g, const void* b, const void* m, const void* v){
    dim3 gr((unsigned)cdivll(N, 64), (unsigned)(Cp / 64));
    k_gemm_mfma<<<gr, 256, 0, stream>>>(in, ik, WTA + off, Kp, bias, of, ob,
                                        N, C, ldc, czero, mode, g, b, m, v, FLAGS);
  };
  int rowsg = (int)cdivll(N, 4);

  // ---- stage A: nn1 MLP; bn0+leaky fused into gemm3 ----
  gemm(x_in, 2, 0,      64,  nn1_b1, A, nullptr, 128, 128, 128, 0, 1, nv, nv, nv, nv);
  gemm(A,    0, 8192,   128, nn1_b2, B, nullptr, 64,  64,  64,  0, 1, nv, nv, nv, nv);
  gemm(B,    0, 16384,  64,  nn1_b3, X, nullptr, 128, 128, 128, 0, 2, bn0_g, bn0_b, bn0_m, bn0_v);

  // ---- GCN1 ----
  gemm(X, 0, 24576, 128, nv, nullptr, HX, 128, 128, 128, 0, 0, nv, nv, nv, nv);
  k_gcn_csr<<<rowsg, 256, 0, stream>>>(ROWP, COLU, HX, DINV, gcn1_b, B, N, 128, FLAGS);

  // ---- GAT1 (fused gather+bias+bn1+leaky+skip -> X) ----
  gemm(B, 0, 40960, 128, nv, nullptr, HX, 640, 640, 640, 0, 0, nv, nv, nv, nv);
  k_attn_dots<<<(int)cdivll((long long)N * HEADS * 64, TB), TB, 0, stream>>>(HX, 128, gat1_as, gat1_ad, AS, AD, N, FLAGS);
  k_gat_alpha<<<rowsg, 256, 0, stream>>>(ROWP, COLU, AS, AD, ALPH, N);
  k_gat_csr<<<rowsg, 256, 0, stream>>>(ROWP, COLU, HX, ALPH, N, 128,
      gat1_b, bn1_g, bn1_b, bn1_m, bn1_v, X, X, FLAGS);

  // ---- GCN2 ----
  gemm(X, 0, 122880, 128, nv, nullptr, HX, 64, 64, 64, 0, 0, nv, nv, nv, nv);
  k_gcn_csr<<<rowsg, 256, 0, stream>>>(ROWP, COLU, HX, DINV, gcn2_b, B, N, 64, FLAGS);

  // ---- GAT2 (fused -> X2) ----
  gemm(B, 0, 131072, 64, nv, nullptr, HX, 320, 320, 320, 0, 0, nv, nv, nv, nv);
  k_attn_dots<<<(int)cdivll((long long)N * HEADS * 64, TB), TB, 0, stream>>>(HX, 64, gat2_as, gat2_ad, AS, AD, N, FLAGS);
  k_gat_alpha<<<rowsg, 256, 0, stream>>>(ROWP, COLU, AS, AD, ALPH, N);
  k_gat_csr<<<rowsg, 256, 0, stream>>>(ROWP, COLU, HX, ALPH, N, 64,
      gat2_b, bn2_g, bn2_b, bn2_m, bn2_v, nullptr, X2, FLAGS);

  // ---- concat -> d_out ----
  k_concat<<<(int)cdivll((long long)N * 192, TB), TB, 0, stream>>>(X, X2, d_out, N, FLAGS);

  // ---- node_pred MLP (all MFMA; mlp2 zero-pads cols to 64, mlp3 uses Kp=64) ----
  gemm(d_out, 2, 151552, 192, mlp_b1, A, nullptr, 96, 128, 96, 0, 1, nv, nv, nv, nv);
  gemm(A,     0, 176128, 96,  mlp_b2, B, nullptr, 48, 64,  64, 64, 1, nv, nv, nv, nv);
  gemm(B,     0, 182272, 64,  mlp_b3, A, nullptr, 24, 64,  24, 0, 1, nv, nv, nv, nv);
  k_final<<<(int)cdivll(N, TB), TB, 0, stream>>>(A, mlp_w4, mlp_b4, d_out, N, FLAGS);
}

// Round 14
// 605.178 us; speedup vs baseline: 1.3108x; 1.0356x over previous
//
#include <hip/hip_runtime.h>
#include <hip/hip_bf16.h>
#include <math.h>
#include <stdint.h>

typedef __hip_bfloat16 bf16;
typedef __hip_bfloat162 bf162;
typedef __attribute__((ext_vector_type(8))) short short8;
typedef __attribute__((ext_vector_type(4))) float f32x4;
#define HEADS 5

static inline long long cdivll(long long a, long long b){ return (a + b - 1) / b; }

__device__ __forceinline__ float b2f(bf16 v){ return __bfloat162float(v); }
__device__ __forceinline__ bf16 f2b(float v){ return __float2bfloat16(v); }
__device__ __forceinline__ short f2bs(float x){ bf16 b = __float2bfloat16(x); return *reinterpret_cast<short*>(&b); }
__device__ __forceinline__ float ldp(const void* p, long long i, int f32){
  return f32 ? ((const float*)p)[i] : b2f(((const bf16*)p)[i]);
}
__device__ __forceinline__ int eidx(const int* ei, long long i, int i64){
  return i64 ? ei[2 * i] : ei[i];
}
__device__ __forceinline__ float lrelu(float x, float a){ return x >= 0.f ? x : a * x; }

// ---------------- runtime dtype detection ----------------
__global__ void k_detect(const unsigned short* xh, const int* ei, int* flags){
  __shared__ int r0[256], r1[256];
  int t = threadIdx.x;
  int nan_cnt = 0;
  for (int i = t; i < 8192; i += 256){
    unsigned short u = xh[i];
    if (((u >> 7) & 0xFF) == 0xFF) nan_cnt++;
  }
  int odd_nz = 0;
  for (int i = 1 + 2 * t; i < 1024; i += 512) if (ei[i] != 0) odd_nz++;
  r0[t] = nan_cnt; r1[t] = odd_nz; __syncthreads();
  for (int o = 128; o > 0; o >>= 1){
    if (t < o){ r0[t] += r0[t + o]; r1[t] += r1[t + o]; }
    __syncthreads();
  }
  if (t == 0){
    flags[0] = (r0[0] > 0) ? 1 : 0;
    flags[1] = (r1[0] == 0) ? 1 : 0;
  }
}

__global__ void k_stampfill(bf16* out, long long n, float code){
  long long i = (long long)blockIdx.x * blockDim.x + threadIdx.x;
  if (i < n) out[i] = f2b(i == 0 ? code : 0.f);
}

__global__ void k_fillf(float* p, float v, long long n){
  long long i = (long long)blockIdx.x * blockDim.x + threadIdx.x;
  if (i < n) p[i] = v;
}

// ---------------- CSR build ----------------
__global__ void k_hist(const int* ei, int E, int N, int* counts, const int* flags){
  int i64 = flags[1];
  int e = blockIdx.x * blockDim.x + threadIdx.x;
  if (e >= E + N) return;
  int d = (e < E) ? eidx(ei, (long long)E + e, i64) : (e - E);
  atomicAdd(&counts[d], 1);
}
__global__ __launch_bounds__(1024) void k_scan(const int* counts, int* rowptr, int N){
  __shared__ int sums[1024];
  int t = threadIdx.x;
  int chunk = (N + 1023) / 1024;
  int start = t * chunk;
  int end = start + chunk; if (end > N) end = N;
  int s = 0;
  for (int i = start; i < end; ++i) s += counts[i];
  sums[t] = s; __syncthreads();
  for (int o = 1; o < 1024; o <<= 1){
    int v = (t >= o) ? sums[t - o] : 0;
    __syncthreads();
    sums[t] += v;
    __syncthreads();
  }
  int run = (t == 0) ? 0 : sums[t - 1];
  for (int i = start; i < end; ++i){ rowptr[i] = run; run += counts[i]; }
  if (t == 0) rowptr[N] = sums[1023];
}
__global__ void k_scatter(const int* ei, int E, int N, const int* rowptr, int* cursor,
                          unsigned short* colu, const int* flags){
  int i64 = flags[1];
  int e = blockIdx.x * blockDim.x + threadIdx.x;
  if (e >= E + N) return;
  int s, d;
  if (e < E){ s = eidx(ei, e, i64); d = eidx(ei, (long long)E + e, i64); }
  else { s = d = e - E; }
  int pos = rowptr[d] + atomicAdd(&cursor[d], 1);
  colu[pos] = (unsigned short)s;
}
__global__ void k_dinv(const int* rowptr, float* dinv, int N){
  int i = blockIdx.x * blockDim.x + threadIdx.x;
  if (i < N) dinv[i] = rsqrtf((float)(rowptr[i + 1] - rowptr[i]));
}

// ------------- pack ALL weights -> WT arena [c][k]; also zeroes CNT/CUR -------------
struct PackDesc { const void* W; int K, Kp, C, Cp, off; };
struct PackArgs { PackDesc d[10]; int total; };
__global__ void k_packall(PackArgs P, bf16* WTA, int* cnt, int ncnt, const int* flags){
  int f32 = flags[0];
  int idx = blockIdx.x * blockDim.x + threadIdx.x;
  if (idx >= P.total){
    int z = idx - P.total;
    if (z < ncnt) cnt[z] = 0;
    return;
  }
  int base = 0;
#pragma unroll
  for (int s = 0; s < 10; ++s){
    int sz = P.d[s].Kp * P.d[s].Cp;
    if (idx < base + sz){
      int local = idx - base;
      int c = local / P.d[s].Kp;
      int k = local - c * P.d[s].Kp;
      float v = (k < P.d[s].K && c < P.d[s].C)
              ? ldp(P.d[s].W, (long long)k * P.d[s].C + c, f32) : 0.f;
      WTA[P.d[s].off + local] = f2b(v);
      return;
    }
    base += sz;
  }
}

// ------------- MFMA GEMM: out[N,C] = act(in[N,Kp] @ WT^T (+bias)) -------------
// Kp % 32 == 0; WT [Cp][Kp] bf16 zero-padded. mode: 0 none, 1 softplus, 2 bias+BN+leaky.
// czero: zero-fill cols [C, czero). Optional fused attention dots: when as_out!=null,
// accumulates AS[n,h]+=sum_c y*aw_s[h,c%chead], AD likewise (head = c0/chead, block-uniform).
__global__ __launch_bounds__(256) void k_gemm_mfma(
    const void* in, int ik, const bf16* WT, int Kp, const void* bias,
    float* outf, bf16* outb, int N, int C, int ldc, int czero, int mode,
    const void* bg, const void* bb, const void* bm, const void* bv,
    float* as_out, float* ad_out, const void* aw_s, const void* aw_d, int chead,
    const int* flags)
{
  int f32 = flags[0];
  int use_b16 = (ik == 1) || (ik == 2 && !f32);
  int t = threadIdx.x;
  int wave = t >> 6, lane = t & 63;
  int quad = lane >> 4, l15 = lane & 15;
  int mbase = blockIdx.x * 64 + wave * 16;
  int c0 = blockIdx.y * 64;
  f32x4 acc[4];
#pragma unroll
  for (int j = 0; j < 4; ++j) acc[j] = (f32x4){0.f, 0.f, 0.f, 0.f};

  int m = mbase + l15; if (m > N - 1) m = N - 1;

  for (int k0 = 0; k0 < Kp; k0 += 32){
    int ka = k0 + quad * 8;
    short8 af;
    if (use_b16){
      af = *(const short8*)((const bf16*)in + (size_t)m * Kp + ka);
    } else {
      const float* p = (const float*)in + (size_t)m * Kp + ka;
      float4 v0 = *(const float4*)p;
      float4 v1 = *(const float4*)(p + 4);
      af[0] = f2bs(v0.x); af[1] = f2bs(v0.y); af[2] = f2bs(v0.z); af[3] = f2bs(v0.w);
      af[4] = f2bs(v1.x); af[5] = f2bs(v1.y); af[6] = f2bs(v1.z); af[7] = f2bs(v1.w);
    }
#pragma unroll
    for (int j = 0; j < 4; ++j){
      short8 bv = *(const short8*)(WT + (size_t)(c0 + 16 * j + l15) * Kp + ka);
      acc[j] = __builtin_amdgcn_mfma_f32_16x16x32_bf16(af, bv, acc[j], 0, 0, 0);
    }
  }
  // ---- store epilogue ----
#pragma unroll
  for (int j = 0; j < 4; ++j){
    int c = c0 + 16 * j + l15;
    if (c < C){
      float bi = bias ? ldp(bias, c, f32) : 0.f;
      float g = 0.f, be = 0.f, mm = 0.f, iv = 0.f;
      if (mode == 2){
        g = ldp(bg, c, f32); be = ldp(bb, c, f32); mm = ldp(bm, c, f32);
        iv = rsqrtf(ldp(bv, c, f32) + 1e-5f);
      }
#pragma unroll
      for (int r = 0; r < 4; ++r){
        int n = mbase + quad * 4 + r;
        if (n >= N) continue;
        float y = acc[j][r] + bi;
        if (mode == 1) y = fmaxf(y, 0.f) + log1pf(expf(-fabsf(y)));
        else if (mode == 2){ y = (y - mm) * iv * g + be; y = lrelu(y, 0.01f); }
        size_t o = (size_t)n * ldc + c;
        if (outb) outb[o] = f2b(y); else outf[o] = y;
      }
    } else if (c < czero){
#pragma unroll
      for (int r = 0; r < 4; ++r){
        int n = mbase + quad * 4 + r;
        if (n >= N) continue;
        size_t o = (size_t)n * ldc + c;
        if (outb) outb[o] = f2b(0.f); else outf[o] = 0.f;
      }
    }
  }
  // ---- fused attention dots (gat gemms: mode 0, no bias, Cp==C) ----
  if (as_out){
    int h = c0 / chead;
    float ws[4], wd[4];
#pragma unroll
    for (int j = 0; j < 4; ++j){
      int cih = (c0 + 16 * j + l15) - h * chead;
      ws[j] = ldp(aw_s, h * chead + cih, f32);
      wd[j] = ldp(aw_d, h * chead + cih, f32);
    }
#pragma unroll
    for (int r = 0; r < 4; ++r){
      float ps = 0.f, pd = 0.f;
#pragma unroll
      for (int j = 0; j < 4; ++j){
        ps = fmaf(acc[j][r], ws[j], ps);
        pd = fmaf(acc[j][r], wd[j], pd);
      }
#pragma unroll
      for (int o = 1; o < 16; o <<= 1){
        ps += __shfl_xor(ps, o);
        pd += __shfl_xor(pd, o);
      }
      int n = mbase + quad * 4 + r;
      if (l15 == 0 && n < N){
        atomicAdd(&as_out[n * HEADS + h], ps);
        atomicAdd(&ad_out[n * HEADS + h], pd);
      }
    }
  }
}

// ------------- GCN aggregate via CSR (h bf16) -------------
__global__ __launch_bounds__(256) void k_gcn_csr(
    const int* rowptr, const unsigned short* colu, const bf16* h,
    const float* dinv, const void* bias, float* out, int N, int C,
    const int* flags)
{
  int f32 = flags[0];
  int wid = (blockIdx.x * 256 + threadIdx.x) >> 6;
  int lane = threadIdx.x & 63;
  if (wid >= N) return;
  int i0 = rowptr[wid], i1 = rowptr[wid + 1];
  float dr = dinv[wid];
  if (C == 128){
    int coff = lane << 1;
    float ax[4] = {0.f, 0.f, 0.f, 0.f}, ay[4] = {0.f, 0.f, 0.f, 0.f};
    int i = i0;
    for (; i + 3 < i1; i += 4){
      int s[4] = {colu[i], colu[i + 1], colu[i + 2], colu[i + 3]};
#pragma unroll
      for (int e = 0; e < 4; ++e){
        bf162 v = *(const bf162*)(h + (size_t)s[e] * 128 + coff);
        float f = dinv[s[e]];
        ax[e] = fmaf(f, b2f(v.x), ax[e]); ay[e] = fmaf(f, b2f(v.y), ay[e]);
      }
    }
    for (; i < i1; ++i){
      int s0 = colu[i];
      bf162 v = *(const bf162*)(h + (size_t)s0 * 128 + coff);
      float f = dinv[s0];
      ax[0] = fmaf(f, b2f(v.x), ax[0]); ay[0] = fmaf(f, b2f(v.y), ay[0]);
    }
    float sx = (ax[0] + ax[1]) + (ax[2] + ax[3]);
    float sy = (ay[0] + ay[1]) + (ay[2] + ay[3]);
    out[(size_t)wid * 128 + coff]     = sx * dr + ldp(bias, coff, f32);
    out[(size_t)wid * 128 + coff + 1] = sy * dr + ldp(bias, coff + 1, f32);
  } else { // C == 64: half-waves, 2 edges per half in flight
    int half = lane >> 5, hl = lane & 31;
    int coff = hl << 1;
    float ax = 0.f, ay = 0.f, bx = 0.f, by = 0.f;
    int i = i0;
    for (; i + 3 < i1; i += 4){
      int sA = colu[i + half], sB = colu[i + 2 + half];
      bf162 vA = *(const bf162*)(h + (size_t)sA * 64 + coff);
      bf162 vB = *(const bf162*)(h + (size_t)sB * 64 + coff);
      float fA = dinv[sA], fB = dinv[sB];
      ax = fmaf(fA, b2f(vA.x), ax); ay = fmaf(fA, b2f(vA.y), ay);
      bx = fmaf(fB, b2f(vB.x), bx); by = fmaf(fB, b2f(vB.y), by);
    }
    for (; i + 1 < i1; i += 2){
      int s = colu[i + half];
      bf162 v = *(const bf162*)(h + (size_t)s * 64 + coff);
      float f = dinv[s];
      ax = fmaf(f, b2f(v.x), ax); ay = fmaf(f, b2f(v.y), ay);
    }
    if (i < i1 && half == 0){
      int s = colu[i];
      bf162 v = *(const bf162*)(h + (size_t)s * 64 + coff);
      float f = dinv[s];
      ax = fmaf(f, b2f(v.x), ax); ay = fmaf(f, b2f(v.y), ay);
    }
    ax += bx; ay += by;
    ax += __shfl_xor(ax, 32);
    ay += __shfl_xor(ay, 32);
    if (half == 0){
      out[(size_t)wid * 64 + coff]     = ax * dr + ldp(bias, coff, f32);
      out[(size_t)wid * 64 + coff + 1] = ay * dr + ldp(bias, coff + 1, f32);
    }
  }
}

// ------------- per-row softmax -> per-edge weights ALPH[slot][5] (1/H folded) -------------
__global__ __launch_bounds__(256) void k_gat_alpha(
    const int* rowptr, const unsigned short* colu,
    const float* as_, const float* ad_, float* alph, int N)
{
  int wid = (blockIdx.x * 256 + threadIdx.x) >> 6;
  int lane = threadIdx.x & 63;
  if (wid >= N) return;
  int i0 = rowptr[wid], i1 = rowptr[wid + 1];
  float adr[HEADS];
#pragma unroll
  for (int h = 0; h < HEADS; ++h) adr[h] = ad_[wid * HEADS + h];
  float m[HEADS];
#pragma unroll
  for (int h = 0; h < HEADS; ++h) m[h] = -INFINITY;
  for (int i = i0 + lane; i < i1; i += 64){
    int s = colu[i];
#pragma unroll
    for (int h = 0; h < HEADS; ++h){
      float e = lrelu(as_[s * HEADS + h] + adr[h], 0.2f);
      m[h] = fmaxf(m[h], e);
    }
  }
#pragma unroll
  for (int h = 0; h < HEADS; ++h)
    for (int o = 32; o > 0; o >>= 1) m[h] = fmaxf(m[h], __shfl_xor(m[h], o));
  float den[HEADS];
#pragma unroll
  for (int h = 0; h < HEADS; ++h) den[h] = 0.f;
  for (int i = i0 + lane; i < i1; i += 64){
    int s = colu[i];
#pragma unroll
    for (int h = 0; h < HEADS; ++h){
      float e = lrelu(as_[s * HEADS + h] + adr[h], 0.2f);
      den[h] += expf(e - m[h]);
    }
  }
#pragma unroll
  for (int h = 0; h < HEADS; ++h){
    for (int o = 32; o > 0; o >>= 1) den[h] += __shfl_xor(den[h], o);
    den[h] = 1.f / (den[h] * (float)HEADS);
  }
  int tot = (i1 - i0) * HEADS;
  for (int idx = lane; idx < tot; idx += 64){
    int sl = idx / HEADS;
    int h = idx - sl * HEADS;
    int i = i0 + sl;
    int s = colu[i];
    float e = lrelu(as_[s * HEADS + h] + adr[h], 0.2f);
    alph[(size_t)i * HEADS + h] = expf(e - m[h]) * den[h];
  }
}

// ------------- fused GAT gather + bias + BN + leaky (+skip) -------------
__global__ __launch_bounds__(256) void k_gat_csr(
    const int* rowptr, const unsigned short* colu, const bf16* hx,
    const float* alph, int N, int C,
    const void* gb, const void* g, const void* bb, const void* bm, const void* bv,
    const float* skip, float* xout, const int* flags)
{
  int f32 = flags[0];
  int wid = (blockIdx.x * 256 + threadIdx.x) >> 6;
  int lane = threadIdx.x & 63;
  if (wid >= N) return;
  int i0 = rowptr[wid], i1 = rowptr[wid + 1];
  int HC = HEADS * C;
  if (C == 128){
    int coff = lane << 1;
    float ax[4] = {0.f, 0.f, 0.f, 0.f}, ay[4] = {0.f, 0.f, 0.f, 0.f};
    int i = i0;
    for (; i + 3 < i1; i += 4){
      int s[4] = {colu[i], colu[i + 1], colu[i + 2], colu[i + 3]};
      const float* a = alph + (size_t)i * HEADS;
#pragma unroll
      for (int e = 0; e < 4; ++e){
        const bf162* r = (const bf162*)(hx + (size_t)s[e] * HC + coff);
#pragma unroll
        for (int h = 0; h < HEADS; ++h){
          bf162 v = r[h * 64];
          float w = a[e * HEADS + h];
          ax[e] = fmaf(w, b2f(v.x), ax[e]); ay[e] = fmaf(w, b2f(v.y), ay[e]);
        }
      }
    }
    for (; i < i1; ++i){
      int s0 = colu[i];
      const bf162* r = (const bf162*)(hx + (size_t)s0 * HC + coff);
      const float* a = alph + (size_t)i * HEADS;
#pragma unroll
      for (int h = 0; h < HEADS; ++h){
        bf162 v = r[h * 64];
        ax[0] = fmaf(a[h], b2f(v.x), ax[0]); ay[0] = fmaf(a[h], b2f(v.y), ay[0]);
      }
    }
    float sx = (ax[0] + ax[1]) + (ax[2] + ax[3]);
    float sy = (ay[0] + ay[1]) + (ay[2] + ay[3]);
#pragma unroll
    for (int j = 0; j < 2; ++j){
      int c = coff + j;
      float y = (j ? sy : sx) + ldp(gb, c, f32);
      y = (y - ldp(bm, c, f32)) * rsqrtf(ldp(bv, c, f32) + 1e-5f) * ldp(g, c, f32) + ldp(bb, c, f32);
      y = lrelu(y, 0.01f);
      if (skip) y += skip[(size_t)wid * C + c];
      xout[(size_t)wid * C + c] = y;
    }
  } else { // C == 64: half-waves, 2 edges per half
    int half = lane >> 5, hl = lane & 31;
    int coff = hl << 1;
    float ax = 0.f, ay = 0.f, bx = 0.f, by = 0.f;
    int i = i0;
    for (; i + 3 < i1; i += 4){
      int sA = colu[i + half], sB = colu[i + 2 + half];
      const bf162* rA = (const bf162*)(hx + (size_t)sA * HC + coff);
      const bf162* rB = (const bf162*)(hx + (size_t)sB * HC + coff);
      const float* aA = alph + (size_t)(i + half) * HEADS;
      const float* aB = alph + (size_t)(i + 2 + half) * HEADS;
#pragma unroll
      for (int h = 0; h < HEADS; ++h){
        bf162 vA = rA[h * 32], vB = rB[h * 32];
        ax = fmaf(aA[h], b2f(vA.x), ax); ay = fmaf(aA[h], b2f(vA.y), ay);
        bx = fmaf(aB[h], b2f(vB.x), bx); by = fmaf(aB[h], b2f(vB.y), by);
      }
    }
    for (; i + 1 < i1; i += 2){
      int s = colu[i + half];
      const bf162* r = (const bf162*)(hx + (size_t)s * HC + coff);
      const float* a = alph + (size_t)(i + half) * HEADS;
#pragma unroll
      for (int h = 0; h < HEADS; ++h){
        bf162 v = r[h * 32];
        ax = fmaf(a[h], b2f(v.x), ax); ay = fmaf(a[h], b2f(v.y), ay);
      }
    }
    if (i < i1 && half == 0){
      int s = colu[i];
      const bf162* r = (const bf162*)(hx + (size_t)s * HC + coff);
      const float* a = alph + (size_t)i * HEADS;
#pragma unroll
      for (int h = 0; h < HEADS; ++h){
        bf162 v = r[h * 32];
        ax = fmaf(a[h], b2f(v.x), ax); ay = fmaf(a[h], b2f(v.y), ay);
      }
    }
    ax += bx; ay += by;
    ax += __shfl_xor(ax, 32);
    ay += __shfl_xor(ay, 32);
    if (half == 0){
#pragma unroll
      for (int j = 0; j < 2; ++j){
        int c = coff + j;
        float y = (j ? ay : ax) + ldp(gb, c, f32);
        y = (y - ldp(bm, c, f32)) * rsqrtf(ldp(bv, c, f32) + 1e-5f) * ldp(g, c, f32) + ldp(bb, c, f32);
        y = lrelu(y, 0.01f);
        if (skip) y += skip[(size_t)wid * C + c];
        xout[(size_t)wid * C + c] = y;
      }
    }
  }
}

__global__ void k_concat(const float* x, const float* x2, void* o, int N, const int* flags)
{
  long long i = (long long)blockIdx.x * blockDim.x + threadIdx.x;
  if (i >= (long long)N * 192) return;
  int n = (int)(i / 192), c = (int)(i - (long long)n * 192);
  float v = (c < 128) ? x[(size_t)n * 128 + c] : x2[(size_t)n * 64 + (c - 128)];
  if (flags[0]) ((float*)o)[i] = v; else ((bf16*)o)[i] = f2b(v);
}

__global__ void k_final(const float* in, const void* w, const void* b, void* o,
                        int N, const int* flags)
{
  int f32 = flags[0];
  int n = blockIdx.x * blockDim.x + threadIdx.x;
  if (n >= N) return;
  float acc = ldp(b, 0, f32);
#pragma unroll
  for (int k = 0; k < 24; ++k) acc = fmaf(in[(size_t)n * 24 + k], ldp(w, k, f32), acc);
  float p = 1.f / (1.f + expf(-acc));
  long long o_i = (long long)N * 192 + n;
  if (f32) ((float*)o)[o_i] = p; else ((bf16*)o)[o_i] = f2b(p);
}

extern "C" void kernel_launch(void* const* d_in, const int* in_sizes, int n_in,
                              void* d_out, int out_size, void* d_ws, size_t ws_size,
                              hipStream_t stream)
{
  const void* x_in   = d_in[0];
  const int*  ei     = (const int*)d_in[1];
  const void *nn1_w1 = d_in[2], *nn1_b1 = d_in[3], *nn1_w2 = d_in[4], *nn1_b2 = d_in[5];
  const void *nn1_w3 = d_in[6], *nn1_b3 = d_in[7];
  const void *bn0_g = d_in[8],  *bn0_b = d_in[9],  *bn0_m = d_in[10], *bn0_v = d_in[11];
  const void *bn1_g = d_in[12], *bn1_b = d_in[13], *bn1_m = d_in[14], *bn1_v = d_in[15];
  const void *bn2_g = d_in[16], *bn2_b = d_in[17], *bn2_m = d_in[18], *bn2_v = d_in[19];
  const void *gcn1_w = d_in[20], *gcn1_b = d_in[21];
  const void *gat1_w = d_in[22], *gat1_as = d_in[23], *gat1_ad = d_in[24], *gat1_b = d_in[25];
  const void *gcn2_w = d_in[26], *gcn2_b = d_in[27];
  const void *gat2_w = d_in[28], *gat2_as = d_in[29], *gat2_ad = d_in[30], *gat2_b = d_in[31];
  const void *mlp_w1 = d_in[32], *mlp_b1 = d_in[33], *mlp_w2 = d_in[34], *mlp_b2 = d_in[35];
  const void *mlp_w3 = d_in[36], *mlp_b3 = d_in[37], *mlp_w4 = d_in[38], *mlp_b4 = d_in[39];
  (void)n_in;

  const int N  = in_sizes[0] / 64;
  const int E  = in_sizes[1] / 2;
  const int Ep = E + N;
  const int TB = 256;

  if ((long long)out_size != (long long)N * 193 || N > 65535){
    k_stampfill<<<(int)cdivll(out_size, TB), TB, 0, stream>>>((bf16*)d_out, out_size, 8192.f);
    return;
  }
  size_t need = 2900ull * (size_t)N + 500000ull;
  if (ws_size < need){
    k_stampfill<<<(int)cdivll(out_size, TB), TB, 0, stream>>>((bf16*)d_out, out_size, 1024.f);
    return;
  }

  // ws layout: flags | X | A | B | DINV | AS | AD | rowptr | colu(u16) | HX(bf16) | WTA(bf16)
  char* wsb = (char*)d_ws;
  int*   FLAGS = (int*)wsb;
  float* X    = (float*)(wsb + 16);
  float* A    = X + (size_t)N * 128;
  float* B    = A + (size_t)N * 128;
  float* DINV = B + (size_t)N * 128;
  float* AS   = DINV + N;
  float* AD   = AS + (size_t)N * HEADS;
  int*   ROWP = (int*)(AD + (size_t)N * HEADS);
  unsigned short* COLU = (unsigned short*)(ROWP + N + 1);
  bf16*  HX   = (bf16*)(COLU + ((Ep + 7) & ~7));
  bf16*  WTA  = (bf16*)(((uintptr_t)(HX + (size_t)N * 640) + 15) & ~(uintptr_t)15);
  float* X2   = A;           // gat2 output lives in A
  float* ALPH = B;           // aliases B (dead once gat gemm consumed B)
  int* CNT = (int*)AS;
  int* CUR = CNT + N;

  k_detect<<<1, 256, 0, stream>>>((const unsigned short*)x_in, ei, FLAGS);

  // ---- pack all weights + zero CNT/CUR ----
  PackArgs P;
  P.d[0] = {nn1_w1,  64, 64, 128, 128, 0};
  P.d[1] = {nn1_w2, 128,128,  64,  64, 8192};
  P.d[2] = {nn1_w3,  64, 64, 128, 128, 16384};
  P.d[3] = {gcn1_w, 128,128, 128, 128, 24576};
  P.d[4] = {gat1_w, 128,128, 640, 640, 40960};
  P.d[5] = {gcn2_w, 128,128,  64,  64, 122880};
  P.d[6] = {gat2_w,  64, 64, 320, 320, 131072};
  P.d[7] = {mlp_w1, 192,192,  96, 128, 151552};
  P.d[8] = {mlp_w2,  96, 96,  48,  64, 176128};
  P.d[9] = {mlp_w3,  48, 64,  24,  64, 182272};
  P.total = 186368;
  k_packall<<<(int)cdivll(P.total + 2 * N, TB), TB, 0, stream>>>(P, WTA, CNT, 2 * N, FLAGS);

  // ---- CSR build ----
  k_hist<<<(int)cdivll(Ep, TB), TB, 0, stream>>>(ei, E, N, CNT, FLAGS);
  k_scan<<<1, 1024, 0, stream>>>(CNT, ROWP, N);
  k_scatter<<<(int)cdivll(Ep, TB), TB, 0, stream>>>(ei, E, N, ROWP, CUR, COLU, FLAGS);
  k_dinv<<<(int)cdivll(N, TB), TB, 0, stream>>>(ROWP, DINV, N);

  const void* nv = nullptr;
  float* nf = nullptr;
  auto gemm = [&](const void* in, int ik, int off, int Kp, const void* bias,
                  float* of, bf16* ob, int C, int Cp, int ldc, int czero, int mode,
                  const void* g, const void* b, const void* m, const void* v,
                  float* aso, float* ado, const void* aws, const void* awd, int chead){
    dim3 gr((unsigned)cdivll(N, 64), (unsigned)(Cp / 64));
    k_gemm_mfma<<<gr, 256, 0, stream>>>(in, ik, WTA + off, Kp, bias, of, ob,
                                        N, C, ldc, czero, mode, g, b, m, v,
                                        aso, ado, aws, awd, chead, FLAGS);
  };
  int rowsg = (int)cdivll(N, 4);

  // ---- stage A: nn1 MLP; bn0+leaky fused into gemm3 ----
  gemm(x_in, 2, 0,      64,  nn1_b1, A, nullptr, 128, 128, 128, 0, 1, nv, nv, nv, nv, nf, nf, nv, nv, 0);
  gemm(A,    0, 8192,   128, nn1_b2, B, nullptr, 64,  64,  64,  0, 1, nv, nv, nv, nv, nf, nf, nv, nv, 0);
  gemm(B,    0, 16384,  64,  nn1_b3, X, nullptr, 128, 128, 128, 0, 2, bn0_g, bn0_b, bn0_m, bn0_v, nf, nf, nv, nv, 0);

  // ---- GCN1 ----
  gemm(X, 0, 24576, 128, nv, nullptr, HX, 128, 128, 128, 0, 0, nv, nv, nv, nv, nf, nf, nv, nv, 0);
  k_gcn_csr<<<rowsg, 256, 0, stream>>>(ROWP, COLU, HX, DINV, gcn1_b, B, N, 128, FLAGS);

  // ---- GAT1 (dots fused into gemm; gather+bias+bn1+leaky+skip fused -> X) ----
  k_fillf<<<(int)cdivll((long long)N * 2 * HEADS, TB), TB, 0, stream>>>(AS, 0.f, (long long)N * 2 * HEADS);
  gemm(B, 0, 40960, 128, nv, nullptr, HX, 640, 640, 640, 0, 0, nv, nv, nv, nv, AS, AD, gat1_as, gat1_ad, 128);
  k_gat_alpha<<<rowsg, 256, 0, stream>>>(ROWP, COLU, AS, AD, ALPH, N);
  k_gat_csr<<<rowsg, 256, 0, stream>>>(ROWP, COLU, HX, ALPH, N, 128,
      gat1_b, bn1_g, bn1_b, bn1_m, bn1_v, X, X, FLAGS);

  // ---- GCN2 ----
  gemm(X, 0, 122880, 128, nv, nullptr, HX, 64, 64, 64, 0, 0, nv, nv, nv, nv, nf, nf, nv, nv, 0);
  k_gcn_csr<<<rowsg, 256, 0, stream>>>(ROWP, COLU, HX, DINV, gcn2_b, B, N, 64, FLAGS);

  // ---- GAT2 (dots fused; gather fused -> X2) ----
  k_fillf<<<(int)cdivll((long long)N * 2 * HEADS, TB), TB, 0, stream>>>(AS, 0.f, (long long)N * 2 * HEADS);
  gemm(B, 0, 131072, 64, nv, nullptr, HX, 320, 320, 320, 0, 0, nv, nv, nv, nv, AS, AD, gat2_as, gat2_ad, 64);
  k_gat_alpha<<<rowsg, 256, 0, stream>>>(ROWP, COLU, AS, AD, ALPH, N);
  k_gat_csr<<<rowsg, 256, 0, stream>>>(ROWP, COLU, HX, ALPH, N, 64,
      gat2_b, bn2_g, bn2_b, bn2_m, bn2_v, nullptr, X2, FLAGS);

  // ---- concat -> d_out ----
  k_concat<<<(int)cdivll((long long)N * 192, TB), TB, 0, stream>>>(X, X2, d_out, N, FLAGS);

  // ---- node_pred MLP ----
  gemm(d_out, 2, 151552, 192, mlp_b1, A, nullptr, 96, 128, 96, 0, 1, nv, nv, nv, nv, nf, nf, nv, nv, 0);
  gemm(A,     0, 176128, 96,  mlp_b2, B, nullptr, 48, 64,  64, 64, 1, nv, nv, nv, nv, nf, nf, nv, nv, 0);
  gemm(B,     0, 182272, 64,  mlp_b3, A, nullptr, 24, 64,  24, 0, 1, nv, nv, nv, nv, nf, nf, nv, nv, 0);
  k_final<<<(int)cdivll(N, TB), TB, 0, stream>>>(A, mlp_w4, mlp_b4, d_out, N, FLAGS);
}